// Round 1
// baseline (1470.378 us; speedup 1.0000x reference)
//
#include <hip/hip_runtime.h>
#include <math.h>

#define D 128
#define D3 384

// ---------- helpers ----------
__device__ __forceinline__ unsigned fenc(float f){
  unsigned u = __float_as_uint(f);
  return (u & 0x80000000u) ? ~u : (u | 0x80000000u);
}
__device__ __forceinline__ float fdec(unsigned k){
  return __uint_as_float((k & 0x80000000u) ? (k & 0x7fffffffu) : ~k);
}
#define ENC_NEGINF 0x007FFFFFu   // fenc(-inf)

__device__ __forceinline__ float sigmoidf_(float x){ return 1.0f / (1.0f + expf(-x)); }

// ---------- init scratch for one GAT layer ----------
__global__ __launch_bounds__(256) void k_init(float* __restrict__ agg, float* __restrict__ ssum,
                                              unsigned* __restrict__ menc, float* __restrict__ bns, int n){
  int idx = blockIdx.x * 256 + threadIdx.x;
  if (idx < n * D) agg[idx] = 0.0f;
  if (idx < n){ ssum[idx] = 0.0f; menc[idx] = ENC_NEGINF; }
  if (idx < 2 * D) bns[idx] = 0.0f;
}

// ---------- time encode: out[i][c] = cos(ts[i]*freq[c]+phase[c]) ----------
__global__ __launch_bounds__(256) void k_timeenc(const float* __restrict__ ts, const float* __restrict__ freq,
                                                 const float* __restrict__ phase, float* __restrict__ out, int n){
  int idx = blockIdx.x * 256 + threadIdx.x;
  if (idx >= n * D) return;
  int i = idx >> 7, c = idx & 127;
  out[idx] = cosf(ts[i] * freq[c] + phase[c]);
}

// ---------- generic fp32 tiled GEMM: C[M,Nc] (+)= A[M,K] @ W[K,Nc] (+ bias) ----------
// BM=BN=64, BK=16, 256 threads, 4x4 per-thread micro-tile.
template<bool ACCUM, bool BIAS>
__global__ __launch_bounds__(256) void k_gemm(const float* __restrict__ A, const float* __restrict__ W,
                                              const float* __restrict__ bias, float* __restrict__ C,
                                              int M, int K, int Nc){
  __shared__ float As[16][68];   // 68: keep 16B row alignment, break store conflicts
  __shared__ float Bs[16][64];
  const int tid = threadIdx.x;
  const int tx = tid & 15, ty = tid >> 4;
  const int row0 = blockIdx.y * 64;
  const int col0 = blockIdx.x * 64;
  const int am = tid >> 2;            // 0..63 (A row within tile)
  const int ak = (tid & 3) * 4;       // 0,4,8,12 (A k within tile)
  const int bk = tid >> 4;            // 0..15  (B k within tile)
  const int bn = (tid & 15) * 4;      // B col within tile
  float acc[4][4] = {};
  const int ntiles = K >> 4;
  for (int t = 0; t < ntiles; ++t){
    const int k0 = t << 4;
    float4 av = make_float4(0.f,0.f,0.f,0.f);
    const int ar = row0 + am;
    if (ar < M) av = *(const float4*)&A[(size_t)ar * K + k0 + ak];
    As[ak+0][am] = av.x; As[ak+1][am] = av.y; As[ak+2][am] = av.z; As[ak+3][am] = av.w;
    *(float4*)&Bs[bk][bn] = *(const float4*)&W[(size_t)(k0 + bk) * Nc + col0 + bn];
    __syncthreads();
    #pragma unroll
    for (int kk = 0; kk < 16; ++kk){
      float4 a4 = *(const float4*)&As[kk][ty * 4];
      float4 b4 = *(const float4*)&Bs[kk][tx * 4];
      float a_[4] = {a4.x, a4.y, a4.z, a4.w};
      float b_[4] = {b4.x, b4.y, b4.z, b4.w};
      #pragma unroll
      for (int i = 0; i < 4; ++i)
        #pragma unroll
        for (int j = 0; j < 4; ++j)
          acc[i][j] = fmaf(a_[i], b_[j], acc[i][j]);
    }
    __syncthreads();
  }
  #pragma unroll
  for (int i = 0; i < 4; ++i){
    const int r = row0 + ty * 4 + i;
    if (r >= M) continue;
    #pragma unroll
    for (int j = 0; j < 4; ++j){
      const int c = col0 + tx * 4 + j;
      float v = acc[i][j];
      if (BIAS) v += bias[c];
      const size_t o = (size_t)r * Nc + c;
      if (ACCUM) v += C[o];
      C[o] = v;
    }
  }
}

// ---------- attention coefficients: asrc[i]=dot(xp[i],a_s), adst[i]=dot(xp[i],a_d) ----------
__global__ __launch_bounds__(256) void k_attn(const float* __restrict__ xp, const float* __restrict__ a_s,
                                              const float* __restrict__ a_d, float* __restrict__ asrc,
                                              float* __restrict__ adst, int n){
  int wave = (blockIdx.x * 256 + threadIdx.x) >> 6;
  int lane = threadIdx.x & 63;
  if (wave >= n) return;
  const float* row = xp + (size_t)wave * D;
  float xa = row[lane], xb = row[lane + 64];
  float sa = xa * a_s[lane] + xb * a_s[lane + 64];
  float sd = xa * a_d[lane] + xb * a_d[lane + 64];
  #pragma unroll
  for (int off = 32; off > 0; off >>= 1){
    sa += __shfl_down(sa, off);
    sd += __shfl_down(sd, off);
  }
  if (lane == 0){ asrc[wave] = sa; adst[wave] = sd; }
}

// ---------- edge pass 1: e = leaky_relu(asrc[src]+adst[dst]); segment max ----------
__global__ __launch_bounds__(256) void k_edge1(const int* __restrict__ ei, const float* __restrict__ asrc,
                                               const float* __restrict__ adst, float* __restrict__ ebuf,
                                               unsigned* __restrict__ menc, int e, int etot){
  int t = blockIdx.x * 256 + threadIdx.x;
  if (t >= etot) return;
  int s_, d_;
  if (t < e){ s_ = ei[t]; d_ = ei[e + t]; } else { s_ = d_ = t - e; }
  float v = asrc[s_] + adst[d_];
  v = (v > 0.0f) ? v : 0.2f * v;
  ebuf[t] = v;
  atomicMax(&menc[d_], fenc(v));
}

// ---------- edge pass 2: ex = exp(e - m[dst]); segment sum ----------
__global__ __launch_bounds__(256) void k_edge2(const int* __restrict__ ei, float* __restrict__ ebuf,
                                               const unsigned* __restrict__ menc, float* __restrict__ ssum,
                                               int e, int etot){
  int t = blockIdx.x * 256 + threadIdx.x;
  if (t >= etot) return;
  int d_ = (t < e) ? ei[e + t] : (t - e);
  float ex = expf(ebuf[t] - fdec(menc[d_]));
  ebuf[t] = ex;
  atomicAdd(&ssum[d_], ex);
}

// ---------- edge pass 3: agg[dst][c] += ex * xp[src][c] ----------
__global__ __launch_bounds__(256) void k_edge3(const int* __restrict__ ei, const float* __restrict__ ebuf,
                                               const float* __restrict__ xp, float* __restrict__ agg,
                                               int e, int etot){
  long long idx = (long long)blockIdx.x * 256 + threadIdx.x;
  int edge = (int)(idx >> 7);
  if (edge >= etot) return;
  int c = (int)(idx & 127);
  int s_, d_;
  if (edge < e){ s_ = ei[edge]; d_ = ei[e + edge]; } else { s_ = d_ = edge - e; }
  float v = ebuf[edge] * xp[(size_t)s_ * D + c];
  atomicAdd(&agg[(size_t)d_ * D + c], v);
}

// ---------- GAT epilogue: h = agg/(s+1e-16) + b (in place) ----------
__global__ __launch_bounds__(256) void k_gatfin(float* __restrict__ agg, const float* __restrict__ ssum,
                                                const float* __restrict__ b, int n){
  int idx = blockIdx.x * 256 + threadIdx.x;
  if (idx >= n * D) return;
  int i = idx >> 7, c = idx & 127;
  agg[idx] = agg[idx] / (ssum[i] + 1e-16f) + b[c];
}

// ---------- GRU combine (elementwise) ----------
__global__ __launch_bounds__(256) void k_gru(const float* __restrict__ gi, const float* __restrict__ gh,
                                             const float* __restrict__ hprev, float* __restrict__ out,
                                             int do_relu, int n){
  int idx = blockIdx.x * 256 + threadIdx.x;
  if (idx >= n * D) return;
  int i = idx >> 7, c = idx & 127;
  const float* gir = gi + (size_t)i * D3;
  const float* ghr = gh + (size_t)i * D3;
  float r = sigmoidf_(gir[c] + ghr[c]);
  float z = sigmoidf_(gir[c + D] + ghr[c + D]);
  float nn = tanhf(gir[c + 2*D] + r * ghr[c + 2*D]);
  float h = (1.0f - z) * nn + z * hprev[idx];
  if (do_relu) h = fmaxf(h, 0.0f);
  out[idx] = h;
}

// ---------- BatchNorm: column sums / sumsq ----------
__global__ __launch_bounds__(256) void k_bnreduce(const float* __restrict__ H, float* __restrict__ bns, int n){
  int c = threadIdx.x & 127;
  int half = threadIdx.x >> 7;
  int r0 = blockIdx.x * 128;
  int rend = min(r0 + 128, n);
  float s0 = 0.0f, s1 = 0.0f;
  for (int r = r0 + half; r < rend; r += 2){
    float v = H[(size_t)r * D + c];
    s0 += v; s1 += v * v;
  }
  __shared__ float sm[2][128];
  if (half){ sm[0][c] = s0; sm[1][c] = s1; }
  __syncthreads();
  if (!half){
    s0 += sm[0][c]; s1 += sm[1][c];
    atomicAdd(&bns[c], s0);
    atomicAdd(&bns[D + c], s1);
  }
}

// ---------- BatchNorm normalize (in place) ----------
__global__ __launch_bounds__(256) void k_bnnorm(float* __restrict__ H, const float* __restrict__ bns, int n){
  int idx = blockIdx.x * 256 + threadIdx.x;
  if (idx >= n * D) return;
  int c = idx & 127;
  float inv_n = 1.0f / (float)n;
  float mu = bns[c] * inv_n;
  float var = bns[D + c] * inv_n - mu * mu;
  H[idx] = (H[idx] - mu) / sqrtf(var + 1e-5f);
}

// ---------- launch ----------
extern "C" void kernel_launch(void* const* d_in, const int* in_sizes, int n_in,
                              void* d_out, int out_size, void* d_ws, size_t ws_size,
                              hipStream_t stream){
  const float* nf     = (const float*)d_in[0];
  const int*   ei     = (const int*)  d_in[1];
  const float* xprev[2] = { (const float*)d_in[2], (const float*)d_in[3] };
  const float* ts     = (const float*)d_in[4];
  const float* freq   = (const float*)d_in[5];
  const float* phase  = (const float*)d_in[6];
  const float* mergeW = (const float*)d_in[7];
  const float* mergeb = (const float*)d_in[8];
  const float* gatW[2]  = { (const float*)d_in[9],  (const float*)d_in[17] };
  const float* gatAS[2] = { (const float*)d_in[10], (const float*)d_in[18] };
  const float* gatAD[2] = { (const float*)d_in[11], (const float*)d_in[19] };
  const float* gatB[2]  = { (const float*)d_in[12], (const float*)d_in[20] };
  const float* Wih[2]   = { (const float*)d_in[13], (const float*)d_in[21] };
  const float* Whh[2]   = { (const float*)d_in[14], (const float*)d_in[22] };
  const float* bih[2]   = { (const float*)d_in[15], (const float*)d_in[23] };
  const float* bhh[2]   = { (const float*)d_in[16], (const float*)d_in[24] };
  const float* skipW  = (const float*)d_in[25];
  const float* skipb  = (const float*)d_in[26];

  const int n = in_sizes[0] / D;      // 50000
  const int e = in_sizes[1] / 2;      // 640000
  const int etot = e + n;             // 690000
  const size_t nd = (size_t)n * D;

  // workspace carve (floats). total ~58.5M floats = 234 MB
  float* ws   = (float*)d_ws;
  float* x    = ws;                       // nd
  float* xp   = x + nd;                   // nd
  float* agg  = xp + nd;                  // nd
  float* gi   = agg + nd;                 // n*3D (also t_embed staging)
  float* gh   = gi + (size_t)n * D3;      // n*3D
  float* ebuf = gh + (size_t)n * D3;      // etot
  float* asrc = ebuf + etot;              // n
  float* adst = asrc + n;                 // n
  float* ssum = adst + n;                 // n
  unsigned* menc = (unsigned*)(ssum + n); // n
  float* bns  = (float*)(menc + n);       // 2*D

  float* H1 = (float*)d_out;
  float* H2 = H1 + nd;

  const dim3 b256(256);
  const int nb_nd = (int)((nd + 255) / 256);
  const int nb_e  = (etot + 255) / 256;
  const int nb_ec = (int)(((size_t)etot * D + 255) / 256);
  const int grows = (n + 63) / 64;
  const dim3 g1(D / 64, grows);    // Nc=128
  const dim3 g3(D3 / 64, grows);   // Nc=384

  // x = [nf, t_embed] @ mergeW + mergeb   (t_embed staged in gi)
  k_timeenc<<<nb_nd, b256, 0, stream>>>(ts, freq, phase, gi, n);
  k_gemm<false,true ><<<g1, b256, 0, stream>>>(nf, mergeW,                 mergeb, x, n, D, D);
  k_gemm<true ,false><<<g1, b256, 0, stream>>>(gi, mergeW + (size_t)D * D, nullptr, x, n, D, D);

  for (int L = 0; L < 2; ++L){
    const float* gin = (L == 0) ? x : H1;
    float* gout = (L == 0) ? H1 : H2;
    k_init<<<nb_nd, b256, 0, stream>>>(agg, ssum, menc, bns, n);
    k_gemm<false,false><<<g1, b256, 0, stream>>>(gin, gatW[L], nullptr, xp, n, D, D);
    k_attn<<<(int)(((size_t)n * 64 + 255) / 256), b256, 0, stream>>>(xp, gatAS[L], gatAD[L], asrc, adst, n);
    k_edge1<<<nb_e, b256, 0, stream>>>(ei, asrc, adst, ebuf, menc, e, etot);
    k_edge2<<<nb_e, b256, 0, stream>>>(ei, ebuf, menc, ssum, e, etot);
    k_edge3<<<nb_ec, b256, 0, stream>>>(ei, ebuf, xp, agg, e, etot);
    k_gatfin<<<nb_nd, b256, 0, stream>>>(agg, ssum, gatB[L], n);
    k_gemm<false,true><<<g3, b256, 0, stream>>>(agg,      Wih[L], bih[L], gi, n, D, D3);
    k_gemm<false,true><<<g3, b256, 0, stream>>>(xprev[L], Whh[L], bhh[L], gh, n, D, D3);
    k_gru<<<nb_nd, b256, 0, stream>>>(gi, gh, xprev[L], gout, (L == 0) ? 1 : 0, n);
  }

  // skip: H2 += x @ skipW + skipb
  k_gemm<true,true><<<g1, b256, 0, stream>>>(x, skipW, skipb, H2, n, D, D);
  // BatchNorm (training stats, identity affine)
  k_bnreduce<<<(n + 127) / 128, b256, 0, stream>>>(H2, bns, n);
  k_bnnorm<<<nb_nd, b256, 0, stream>>>(H2, bns, n);
}

// Round 2
// 910.864 us; speedup vs baseline: 1.6143x; 1.6143x over previous
//
#include <hip/hip_runtime.h>
#include <math.h>

#define D 128
#define D3 384

__device__ __forceinline__ float sigmoidf_(float x){ return 1.0f / (1.0f + expf(-x)); }

// ---------- zero small scratch ----------
__global__ __launch_bounds__(256) void k_init0(int* __restrict__ cnt, float* __restrict__ bns, int n){
  int idx = blockIdx.x * 256 + threadIdx.x;
  if (idx < n) cnt[idx] = 0;
  if (idx < 2 * D) bns[idx] = 0.0f;
}

// ---------- time encode: out[i][c] = cos(ts[i]*freq[c]+phase[c]) ----------
__global__ __launch_bounds__(256) void k_timeenc(const float* __restrict__ ts, const float* __restrict__ freq,
                                                 const float* __restrict__ phase, float* __restrict__ out, int n){
  int idx = blockIdx.x * 256 + threadIdx.x;
  if (idx >= n * D) return;
  int i = idx >> 7, c = idx & 127;
  out[idx] = cosf(ts[i] * freq[c] + phase[c]);
}

// ---------- generic fp32 tiled GEMM: C[M,Nc] (+)= A[M,K] @ W[K,Nc] (+ bias) ----------
template<bool ACCUM, bool BIAS>
__global__ __launch_bounds__(256) void k_gemm(const float* __restrict__ A, const float* __restrict__ W,
                                              const float* __restrict__ bias, float* __restrict__ C,
                                              int M, int K, int Nc){
  __shared__ float As[16][68];
  __shared__ float Bs[16][64];
  const int tid = threadIdx.x;
  const int tx = tid & 15, ty = tid >> 4;
  const int row0 = blockIdx.y * 64;
  const int col0 = blockIdx.x * 64;
  const int am = tid >> 2;
  const int ak = (tid & 3) * 4;
  const int bk = tid >> 4;
  const int bn = (tid & 15) * 4;
  float acc[4][4] = {};
  const int ntiles = K >> 4;
  for (int t = 0; t < ntiles; ++t){
    const int k0 = t << 4;
    float4 av = make_float4(0.f,0.f,0.f,0.f);
    const int ar = row0 + am;
    if (ar < M) av = *(const float4*)&A[(size_t)ar * K + k0 + ak];
    As[ak+0][am] = av.x; As[ak+1][am] = av.y; As[ak+2][am] = av.z; As[ak+3][am] = av.w;
    *(float4*)&Bs[bk][bn] = *(const float4*)&W[(size_t)(k0 + bk) * Nc + col0 + bn];
    __syncthreads();
    #pragma unroll
    for (int kk = 0; kk < 16; ++kk){
      float4 a4 = *(const float4*)&As[kk][ty * 4];
      float4 b4 = *(const float4*)&Bs[kk][tx * 4];
      float a_[4] = {a4.x, a4.y, a4.z, a4.w};
      float b_[4] = {b4.x, b4.y, b4.z, b4.w};
      #pragma unroll
      for (int i = 0; i < 4; ++i)
        #pragma unroll
        for (int j = 0; j < 4; ++j)
          acc[i][j] = fmaf(a_[i], b_[j], acc[i][j]);
    }
    __syncthreads();
  }
  #pragma unroll
  for (int i = 0; i < 4; ++i){
    const int r = row0 + ty * 4 + i;
    if (r >= M) continue;
    #pragma unroll
    for (int j = 0; j < 4; ++j){
      const int c = col0 + tx * 4 + j;
      float v = acc[i][j];
      if (BIAS) v += bias[c];
      const size_t o = (size_t)r * Nc + c;
      if (ACCUM) v += C[o];
      C[o] = v;
    }
  }
}

// ---------- attention coefficients ----------
__global__ __launch_bounds__(256) void k_attn(const float* __restrict__ xp, const float* __restrict__ a_s,
                                              const float* __restrict__ a_d, float* __restrict__ asrc,
                                              float* __restrict__ adst, int n){
  int wave = (blockIdx.x * 256 + threadIdx.x) >> 6;
  int lane = threadIdx.x & 63;
  if (wave >= n) return;
  const float* row = xp + (size_t)wave * D;
  float xa = row[lane], xb = row[lane + 64];
  float sa = xa * a_s[lane] + xb * a_s[lane + 64];
  float sd = xa * a_d[lane] + xb * a_d[lane + 64];
  #pragma unroll
  for (int off = 32; off > 0; off >>= 1){
    sa += __shfl_down(sa, off);
    sd += __shfl_down(sd, off);
  }
  if (lane == 0){ asrc[wave] = sa; adst[wave] = sd; }
}

// ---------- CSR build: histogram of dst ----------
__global__ __launch_bounds__(256) void k_hist(const int* __restrict__ ei, int* __restrict__ cnt, int e, int etot){
  int t = blockIdx.x * 256 + threadIdx.x;
  if (t >= etot) return;
  int d_ = (t < e) ? ei[e + t] : (t - e);
  atomicAdd(&cnt[d_], 1);
}

// ---------- scan stage 1: per-block exclusive scan + block sums ----------
__global__ __launch_bounds__(256) void k_scan1(const int* __restrict__ cnt, int* __restrict__ off,
                                               int* __restrict__ bsum, int n){
  __shared__ int sm[256];
  int i = blockIdx.x * 256 + threadIdx.x;
  int v = (i < n) ? cnt[i] : 0;
  sm[threadIdx.x] = v;
  __syncthreads();
  #pragma unroll
  for (int d = 1; d < 256; d <<= 1){
    int t = (threadIdx.x >= d) ? sm[threadIdx.x - d] : 0;
    __syncthreads();
    sm[threadIdx.x] += t;
    __syncthreads();
  }
  if (i < n) off[i] = sm[threadIdx.x] - v;
  if (threadIdx.x == 255) bsum[blockIdx.x] = sm[255];
}

// ---------- scan stage 2: single-block exclusive scan of block sums ----------
__global__ __launch_bounds__(256) void k_scan2(int* __restrict__ bsum, int nb){
  __shared__ int sm[256];
  int v = (threadIdx.x < nb) ? bsum[threadIdx.x] : 0;
  sm[threadIdx.x] = v;
  __syncthreads();
  #pragma unroll
  for (int d = 1; d < 256; d <<= 1){
    int t = (threadIdx.x >= d) ? sm[threadIdx.x - d] : 0;
    __syncthreads();
    sm[threadIdx.x] += t;
    __syncthreads();
  }
  if (threadIdx.x < nb) bsum[threadIdx.x] = sm[threadIdx.x] - v;
}

// ---------- scan stage 3: add block offsets; init cursor; off[n]=etot ----------
__global__ __launch_bounds__(256) void k_scan3(int* __restrict__ off, const int* __restrict__ bsum,
                                               int* __restrict__ cursor, int n, int etot){
  int i = blockIdx.x * 256 + threadIdx.x;
  if (i < n){
    int o = off[i] + bsum[blockIdx.x];
    off[i] = o;
    cursor[i] = o;
  }
  if (i == 0) off[n] = etot;
}

// ---------- CSR scatter: csr[pos] = src ----------
__global__ __launch_bounds__(256) void k_scatter(const int* __restrict__ ei, int* __restrict__ cursor,
                                                 int* __restrict__ csr, int e, int etot){
  int t = blockIdx.x * 256 + threadIdx.x;
  if (t >= etot) return;
  int s_, d_;
  if (t < e){ s_ = ei[t]; d_ = ei[e + t]; } else { s_ = d_ = t - e; }
  int pos = atomicAdd(&cursor[d_], 1);
  csr[pos] = s_;
}

// ---------- fused GAT edge phase: one wave per dst node, gather over CSR ----------
__global__ __launch_bounds__(256) void k_gatconv(const int* __restrict__ off, const int* __restrict__ csr,
                                                 const float* __restrict__ asrc, const float* __restrict__ adst,
                                                 const float* __restrict__ xp, const float* __restrict__ bias,
                                                 float* __restrict__ out, int n){
  int w = (blockIdx.x * 256 + threadIdx.x) >> 6;
  int lane = threadIdx.x & 63;
  if (w >= n) return;
  const int o0 = off[w], o1 = off[w + 1];
  const float ad = adst[w];
  // pass 1: segment max (lane-strided)
  float m = -1e30f;
  for (int j = o0 + lane; j < o1; j += 64){
    float v = asrc[csr[j]] + ad;
    v = (v > 0.0f) ? v : 0.2f * v;
    m = fmaxf(m, v);
  }
  #pragma unroll
  for (int d = 32; d > 0; d >>= 1) m = fmaxf(m, __shfl_xor(m, d));
  // pass 2: fused exp-sum + weighted aggregation (serial over edges, lanes = channels)
  float s = 0.0f, acc0 = 0.0f, acc1 = 0.0f;
  int src_next = csr[o0];
  for (int j = o0; j < o1; ++j){
    int src = src_next;
    if (j + 1 < o1) src_next = csr[j + 1];
    float v = asrc[src] + ad;
    v = (v > 0.0f) ? v : 0.2f * v;
    float wgt = expf(v - m);
    s += wgt;
    const float* row = xp + (size_t)src * D;
    acc0 = fmaf(wgt, row[lane], acc0);
    acc1 = fmaf(wgt, row[lane + 64], acc1);
  }
  float inv = 1.0f / (s + 1e-16f);
  out[(size_t)w * D + lane]      = acc0 * inv + bias[lane];
  out[(size_t)w * D + 64 + lane] = acc1 * inv + bias[lane + 64];
}

// ---------- GRU combine (elementwise) ----------
__global__ __launch_bounds__(256) void k_gru(const float* __restrict__ gi, const float* __restrict__ gh,
                                             const float* __restrict__ hprev, float* __restrict__ out,
                                             int do_relu, int n){
  int idx = blockIdx.x * 256 + threadIdx.x;
  if (idx >= n * D) return;
  int i = idx >> 7, c = idx & 127;
  const float* gir = gi + (size_t)i * D3;
  const float* ghr = gh + (size_t)i * D3;
  float r = sigmoidf_(gir[c] + ghr[c]);
  float z = sigmoidf_(gir[c + D] + ghr[c + D]);
  float nn = tanhf(gir[c + 2*D] + r * ghr[c + 2*D]);
  float h = (1.0f - z) * nn + z * hprev[idx];
  if (do_relu) h = fmaxf(h, 0.0f);
  out[idx] = h;
}

// ---------- BatchNorm: column sums / sumsq ----------
__global__ __launch_bounds__(256) void k_bnreduce(const float* __restrict__ H, float* __restrict__ bns, int n){
  int c = threadIdx.x & 127;
  int half = threadIdx.x >> 7;
  int r0 = blockIdx.x * 128;
  int rend = min(r0 + 128, n);
  float s0 = 0.0f, s1 = 0.0f;
  for (int r = r0 + half; r < rend; r += 2){
    float v = H[(size_t)r * D + c];
    s0 += v; s1 += v * v;
  }
  __shared__ float sm[2][128];
  if (half){ sm[0][c] = s0; sm[1][c] = s1; }
  __syncthreads();
  if (!half){
    s0 += sm[0][c]; s1 += sm[1][c];
    atomicAdd(&bns[c], s0);
    atomicAdd(&bns[D + c], s1);
  }
}

// ---------- BatchNorm normalize (in place) ----------
__global__ __launch_bounds__(256) void k_bnnorm(float* __restrict__ H, const float* __restrict__ bns, int n){
  int idx = blockIdx.x * 256 + threadIdx.x;
  if (idx >= n * D) return;
  int c = idx & 127;
  float inv_n = 1.0f / (float)n;
  float mu = bns[c] * inv_n;
  float var = bns[D + c] * inv_n - mu * mu;
  H[idx] = (H[idx] - mu) / sqrtf(var + 1e-5f);
}

// ---------- launch ----------
extern "C" void kernel_launch(void* const* d_in, const int* in_sizes, int n_in,
                              void* d_out, int out_size, void* d_ws, size_t ws_size,
                              hipStream_t stream){
  const float* nf     = (const float*)d_in[0];
  const int*   ei     = (const int*)  d_in[1];
  const float* xprev[2] = { (const float*)d_in[2], (const float*)d_in[3] };
  const float* ts     = (const float*)d_in[4];
  const float* freq   = (const float*)d_in[5];
  const float* phase  = (const float*)d_in[6];
  const float* mergeW = (const float*)d_in[7];
  const float* mergeb = (const float*)d_in[8];
  const float* gatW[2]  = { (const float*)d_in[9],  (const float*)d_in[17] };
  const float* gatAS[2] = { (const float*)d_in[10], (const float*)d_in[18] };
  const float* gatAD[2] = { (const float*)d_in[11], (const float*)d_in[19] };
  const float* gatB[2]  = { (const float*)d_in[12], (const float*)d_in[20] };
  const float* Wih[2]   = { (const float*)d_in[13], (const float*)d_in[21] };
  const float* Whh[2]   = { (const float*)d_in[14], (const float*)d_in[22] };
  const float* bih[2]   = { (const float*)d_in[15], (const float*)d_in[23] };
  const float* bhh[2]   = { (const float*)d_in[16], (const float*)d_in[24] };
  const float* skipW  = (const float*)d_in[25];
  const float* skipb  = (const float*)d_in[26];

  const int n = in_sizes[0] / D;      // 50000
  const int e = in_sizes[1] / 2;      // 640000
  const int etot = e + n;             // 690000
  const size_t nd = (size_t)n * D;

  // workspace carve (4-byte words). ~208 MB total.
  float* ws   = (float*)d_ws;
  float* x    = ws;                        // nd
  float* xp   = x + nd;                    // nd
  float* gi   = xp + nd;                   // n*3D
  float* gh   = gi + (size_t)n * D3;       // n*3D  (first nd doubles as GAT output hg)
  float* hg   = gh;                        //   alias: hg consumed before gh is written
  float* asrc = gh + (size_t)n * D3;       // n
  float* adst = asrc + n;                  // n
  float* bns  = adst + n;                  // 2*D
  int*   off  = (int*)(bns + 2 * D);       // n+1
  int*   cnt  = off + n + 1;               // n (histogram, then cursor)
  int*   bsum = cnt + n;                   // 256
  int*   csr  = bsum + 256;                // etot

  float* H1 = (float*)d_out;
  float* H2 = H1 + nd;

  const dim3 b256(256);
  const int nb_nd = (int)((nd + 255) / 256);
  const int nb_e  = (etot + 255) / 256;
  const int nb_n  = (n + 255) / 256;       // 196 blocks (<= 256 for scan2)
  const int grows = (n + 63) / 64;
  const dim3 g1(D / 64, grows);
  const dim3 g3(D3 / 64, grows);

  // ---- CSR build (dst-sorted gather lists; reused by both layers) ----
  k_init0<<<nb_n, b256, 0, stream>>>(cnt, bns, n);
  k_hist<<<nb_e, b256, 0, stream>>>(ei, cnt, e, etot);
  k_scan1<<<nb_n, b256, 0, stream>>>(cnt, off, bsum, n);
  k_scan2<<<1, b256, 0, stream>>>(bsum, nb_n);
  k_scan3<<<nb_n, b256, 0, stream>>>(off, bsum, cnt, n, etot);
  k_scatter<<<nb_e, b256, 0, stream>>>(ei, cnt, csr, e, etot);

  // ---- x = [nf, t_embed] @ mergeW + mergeb  (t_embed staged in gi) ----
  k_timeenc<<<nb_nd, b256, 0, stream>>>(ts, freq, phase, gi, n);
  k_gemm<false,true ><<<g1, b256, 0, stream>>>(nf, mergeW,                 mergeb, x, n, D, D);
  k_gemm<true ,false><<<g1, b256, 0, stream>>>(gi, mergeW + (size_t)D * D, nullptr, x, n, D, D);

  for (int L = 0; L < 2; ++L){
    const float* gin = (L == 0) ? x : H1;
    float* gout = (L == 0) ? H1 : H2;
    k_gemm<false,false><<<g1, b256, 0, stream>>>(gin, gatW[L], nullptr, xp, n, D, D);
    k_attn<<<(int)(((size_t)n * 64 + 255) / 256), b256, 0, stream>>>(xp, gatAS[L], gatAD[L], asrc, adst, n);
    k_gatconv<<<(int)(((size_t)n * 64 + 255) / 256), b256, 0, stream>>>(off, csr, asrc, adst, xp, gatB[L], hg, n);
    k_gemm<false,true><<<g3, b256, 0, stream>>>(hg,       Wih[L], bih[L], gi, n, D, D3);
    k_gemm<false,true><<<g3, b256, 0, stream>>>(xprev[L], Whh[L], bhh[L], gh, n, D, D3);
    k_gru<<<nb_nd, b256, 0, stream>>>(gi, gh, xprev[L], gout, (L == 0) ? 1 : 0, n);
  }

  // skip: H2 += x @ skipW + skipb
  k_gemm<true,true><<<g1, b256, 0, stream>>>(x, skipW, skipb, H2, n, D, D);
  // BatchNorm (training stats, identity affine)
  k_bnreduce<<<(n + 127) / 128, b256, 0, stream>>>(H2, bns, n);
  k_bnnorm<<<nb_nd, b256, 0, stream>>>(H2, bns, n);
}

// Round 3
// 762.210 us; speedup vs baseline: 1.9291x; 1.1950x over previous
//
#include <hip/hip_runtime.h>
#include <math.h>

#define D 128
#define D3 384

typedef __attribute__((ext_vector_type(8))) short bf16x8;
typedef __attribute__((ext_vector_type(4))) float f32x4;
typedef __attribute__((ext_vector_type(4))) unsigned int u32x4;

__device__ __forceinline__ float sigmoidf_(float x){ return 1.0f / (1.0f + expf(-x)); }

// round-to-nearest-even f32 -> bf16
__device__ __forceinline__ unsigned short f2bf(float f){
  unsigned u = __float_as_uint(f);
  return (unsigned short)((u + 0x7FFFu + ((u >> 16) & 1u)) >> 16);
}

// ---------- zero small scratch ----------
__global__ __launch_bounds__(256) void k_init0(int* __restrict__ cnt, float* __restrict__ bns, int n){
  int idx = blockIdx.x * 256 + threadIdx.x;
  if (idx < n) cnt[idx] = 0;
  if (idx < 2 * D) bns[idx] = 0.0f;
}

// ---------- time encode ----------
__global__ __launch_bounds__(256) void k_timeenc(const float* __restrict__ ts, const float* __restrict__ freq,
                                                 const float* __restrict__ phase, float* __restrict__ out, int n){
  int idx = blockIdx.x * 256 + threadIdx.x;
  if (idx >= n * D) return;
  int i = idx >> 7, c = idx & 127;
  out[idx] = cosf(ts[i] * freq[c] + phase[c]);
}

// ---------- weight convert+transpose: Wt[c][k] = bf16(W[k][c]), K=128 ----------
__global__ __launch_bounds__(256) void k_wcvt(const float* __restrict__ W, unsigned short* __restrict__ Wt, int Nc){
  int idx = blockIdx.x * 256 + threadIdx.x;
  if (idx >= 128 * Nc) return;
  int k = idx / Nc, c = idx - k * Nc;
  Wt[c * 128 + k] = f2bf(W[idx]);
}

// ---------- bf16 MFMA GEMM: C[M,Nc] (+)= A[M,128] @ Bt^T (+ bias) ----------
// A: f32 [M][128] (converted on the fly). Bt: bf16 [Nc][128] (pre-transposed).
// BM=64, BN=128, 256 threads = 4 waves; wave w owns cols [w*32, w*32+32).
template<bool ACCUM, bool BIAS>
__global__ __launch_bounds__(256) void k_mgemm(const float* __restrict__ A,
                                               const unsigned short* __restrict__ Bt,
                                               const float* __restrict__ bias,
                                               float* __restrict__ C, int M, int Nc){
  __shared__ __align__(16) unsigned short Alds[64 * 128];
  __shared__ __align__(16) unsigned short Blds[128 * 128];
  const int tid = threadIdx.x;
  const int lane = tid & 63;
  const int w = tid >> 6;
  const int row0 = blockIdx.y * 64;
  const int col0 = blockIdx.x * 128;

  // ---- stage A (f32 -> bf16, XOR-swizzled 16B units) ----
  #pragma unroll
  for (int r = 0; r < 4; ++r){
    int u = r * 256 + tid;
    int row = u >> 4, c16 = u & 15;
    int gr = row0 + row;
    float4 f0 = make_float4(0.f,0.f,0.f,0.f), f1 = f0;
    if (gr < M){
      const float* p = A + (size_t)gr * 128 + c16 * 8;
      f0 = *(const float4*)p;
      f1 = *(const float4*)(p + 4);
    }
    union { unsigned short s[8]; bf16x8 v; } t;
    t.s[0]=f2bf(f0.x); t.s[1]=f2bf(f0.y); t.s[2]=f2bf(f0.z); t.s[3]=f2bf(f0.w);
    t.s[4]=f2bf(f1.x); t.s[5]=f2bf(f1.y); t.s[6]=f2bf(f1.z); t.s[7]=f2bf(f1.w);
    int c16s = c16 ^ (row & 7);
    *(bf16x8*)&Alds[row * 128 + c16s * 8] = t.v;
  }
  // ---- stage B (already bf16, XOR-swizzled) ----
  #pragma unroll
  for (int r = 0; r < 8; ++r){
    int u = r * 256 + tid;
    int row = u >> 4, c16 = u & 15;
    u32x4 v = *(const u32x4*)(Bt + (size_t)(col0 + row) * 128 + c16 * 8);
    int c16s = c16 ^ (row & 7);
    *(u32x4*)&Blds[row * 128 + c16s * 8] = v;
  }
  __syncthreads();

  // ---- MFMA main: 4 k-steps of 32 ----
  f32x4 acc[4][2];
  #pragma unroll
  for (int mf = 0; mf < 4; ++mf)
    #pragma unroll
    for (int nf = 0; nf < 2; ++nf)
      #pragma unroll
      for (int i = 0; i < 4; ++i) acc[mf][nf][i] = 0.0f;

  const int l15 = lane & 15, lg = lane >> 4;
  #pragma unroll
  for (int kk = 0; kk < 4; ++kk){
    const int c16 = kk * 4 + lg;
    bf16x8 a[4], b[2];
    #pragma unroll
    for (int mf = 0; mf < 4; ++mf){
      int row = mf * 16 + l15;
      a[mf] = *(bf16x8*)&Alds[row * 128 + ((c16 ^ (row & 7))) * 8];
    }
    #pragma unroll
    for (int nf = 0; nf < 2; ++nf){
      int row = w * 32 + nf * 16 + l15;
      b[nf] = *(bf16x8*)&Blds[row * 128 + ((c16 ^ (row & 7))) * 8];
    }
    #pragma unroll
    for (int mf = 0; mf < 4; ++mf)
      #pragma unroll
      for (int nf = 0; nf < 2; ++nf)
        acc[mf][nf] = __builtin_amdgcn_mfma_f32_16x16x32_bf16(a[mf], b[nf], acc[mf][nf], 0, 0, 0);
  }

  // ---- epilogue: C[row][col], col = lane&15-indexed, row = (lane>>4)*4 + reg ----
  #pragma unroll
  for (int nf = 0; nf < 2; ++nf){
    int c = col0 + w * 32 + nf * 16 + l15;
    float bv = BIAS ? bias[c] : 0.0f;
    #pragma unroll
    for (int mf = 0; mf < 4; ++mf){
      #pragma unroll
      for (int i = 0; i < 4; ++i){
        int rr = row0 + mf * 16 + lg * 4 + i;
        if (rr < M){
          size_t o = (size_t)rr * Nc + c;
          float v = acc[mf][nf][i] + bv;
          if (ACCUM) v += C[o];
          C[o] = v;
        }
      }
    }
  }
}

// ---------- attention coefficients ----------
__global__ __launch_bounds__(256) void k_attn(const float* __restrict__ xp, const float* __restrict__ a_s,
                                              const float* __restrict__ a_d, float* __restrict__ asrc,
                                              float* __restrict__ adst, int n){
  int wave = (blockIdx.x * 256 + threadIdx.x) >> 6;
  int lane = threadIdx.x & 63;
  if (wave >= n) return;
  const float* row = xp + (size_t)wave * D;
  float xa = row[lane], xb = row[lane + 64];
  float sa = xa * a_s[lane] + xb * a_s[lane + 64];
  float sd = xa * a_d[lane] + xb * a_d[lane + 64];
  #pragma unroll
  for (int off = 32; off > 0; off >>= 1){
    sa += __shfl_down(sa, off);
    sd += __shfl_down(sd, off);
  }
  if (lane == 0){ asrc[wave] = sa; adst[wave] = sd; }
}

// ---------- CSR build ----------
__global__ __launch_bounds__(256) void k_hist(const int* __restrict__ ei, int* __restrict__ cnt, int e, int etot){
  int t = blockIdx.x * 256 + threadIdx.x;
  if (t >= etot) return;
  int d_ = (t < e) ? ei[e + t] : (t - e);
  atomicAdd(&cnt[d_], 1);
}

__global__ __launch_bounds__(256) void k_scan1(const int* __restrict__ cnt, int* __restrict__ off,
                                               int* __restrict__ bsum, int n){
  __shared__ int sm[256];
  int i = blockIdx.x * 256 + threadIdx.x;
  int v = (i < n) ? cnt[i] : 0;
  sm[threadIdx.x] = v;
  __syncthreads();
  #pragma unroll
  for (int d = 1; d < 256; d <<= 1){
    int t = (threadIdx.x >= d) ? sm[threadIdx.x - d] : 0;
    __syncthreads();
    sm[threadIdx.x] += t;
    __syncthreads();
  }
  if (i < n) off[i] = sm[threadIdx.x] - v;
  if (threadIdx.x == 255) bsum[blockIdx.x] = sm[255];
}

__global__ __launch_bounds__(256) void k_scan2(int* __restrict__ bsum, int nb){
  __shared__ int sm[256];
  int v = (threadIdx.x < nb) ? bsum[threadIdx.x] : 0;
  sm[threadIdx.x] = v;
  __syncthreads();
  #pragma unroll
  for (int d = 1; d < 256; d <<= 1){
    int t = (threadIdx.x >= d) ? sm[threadIdx.x - d] : 0;
    __syncthreads();
    sm[threadIdx.x] += t;
    __syncthreads();
  }
  if (threadIdx.x < nb) bsum[threadIdx.x] = sm[threadIdx.x] - v;
}

__global__ __launch_bounds__(256) void k_scan3(int* __restrict__ off, const int* __restrict__ bsum,
                                               int* __restrict__ cursor, int n, int etot){
  int i = blockIdx.x * 256 + threadIdx.x;
  if (i < n){
    int o = off[i] + bsum[blockIdx.x];
    off[i] = o;
    cursor[i] = o;
  }
  if (i == 0) off[n] = etot;
}

__global__ __launch_bounds__(256) void k_scatter(const int* __restrict__ ei, int* __restrict__ cursor,
                                                 int* __restrict__ csr, int e, int etot){
  int t = blockIdx.x * 256 + threadIdx.x;
  if (t >= etot) return;
  int s_, d_;
  if (t < e){ s_ = ei[t]; d_ = ei[e + t]; } else { s_ = d_ = t - e; }
  int pos = atomicAdd(&cursor[d_], 1);
  csr[pos] = s_;
}

// ---------- fused GAT edge phase: one wave per dst node ----------
__global__ __launch_bounds__(256) void k_gatconv(const int* __restrict__ off, const int* __restrict__ csr,
                                                 const float* __restrict__ asrc, const float* __restrict__ adst,
                                                 const float* __restrict__ xp, const float* __restrict__ bias,
                                                 float* __restrict__ out, int n){
  int w = (blockIdx.x * 256 + threadIdx.x) >> 6;
  int lane = threadIdx.x & 63;
  if (w >= n) return;
  const int o0 = off[w], o1 = off[w + 1];
  const float ad = adst[w];
  float m = -1e30f;
  for (int j = o0 + lane; j < o1; j += 64){
    float v = asrc[csr[j]] + ad;
    v = (v > 0.0f) ? v : 0.2f * v;
    m = fmaxf(m, v);
  }
  #pragma unroll
  for (int d = 32; d > 0; d >>= 1) m = fmaxf(m, __shfl_xor(m, d));
  float s = 0.0f, acc0 = 0.0f, acc1 = 0.0f;
  int src_next = csr[o0];
  for (int j = o0; j < o1; ++j){
    int src = src_next;
    if (j + 1 < o1) src_next = csr[j + 1];
    float v = asrc[src] + ad;
    v = (v > 0.0f) ? v : 0.2f * v;
    float wgt = expf(v - m);
    s += wgt;
    const float* row = xp + (size_t)src * D;
    acc0 = fmaf(wgt, row[lane], acc0);
    acc1 = fmaf(wgt, row[lane + 64], acc1);
  }
  float inv = 1.0f / (s + 1e-16f);
  out[(size_t)w * D + lane]      = acc0 * inv + bias[lane];
  out[(size_t)w * D + 64 + lane] = acc1 * inv + bias[lane + 64];
}

// ---------- GRU combine ----------
__global__ __launch_bounds__(256) void k_gru(const float* __restrict__ gi, const float* __restrict__ gh,
                                             const float* __restrict__ hprev, float* __restrict__ out,
                                             int do_relu, int n){
  int idx = blockIdx.x * 256 + threadIdx.x;
  if (idx >= n * D) return;
  int i = idx >> 7, c = idx & 127;
  const float* gir = gi + (size_t)i * D3;
  const float* ghr = gh + (size_t)i * D3;
  float r = sigmoidf_(gir[c] + ghr[c]);
  float z = sigmoidf_(gir[c + D] + ghr[c + D]);
  float nn = tanhf(gir[c + 2*D] + r * ghr[c + 2*D]);
  float h = (1.0f - z) * nn + z * hprev[idx];
  if (do_relu) h = fmaxf(h, 0.0f);
  out[idx] = h;
}

// ---------- BatchNorm ----------
__global__ __launch_bounds__(256) void k_bnreduce(const float* __restrict__ H, float* __restrict__ bns, int n){
  int c = threadIdx.x & 127;
  int half = threadIdx.x >> 7;
  int r0 = blockIdx.x * 128;
  int rend = min(r0 + 128, n);
  float s0 = 0.0f, s1 = 0.0f;
  for (int r = r0 + half; r < rend; r += 2){
    float v = H[(size_t)r * D + c];
    s0 += v; s1 += v * v;
  }
  __shared__ float sm[2][128];
  if (half){ sm[0][c] = s0; sm[1][c] = s1; }
  __syncthreads();
  if (!half){
    s0 += sm[0][c]; s1 += sm[1][c];
    atomicAdd(&bns[c], s0);
    atomicAdd(&bns[D + c], s1);
  }
}

__global__ __launch_bounds__(256) void k_bnnorm(float* __restrict__ H, const float* __restrict__ bns, int n){
  int idx = blockIdx.x * 256 + threadIdx.x;
  if (idx >= n * D) return;
  int c = idx & 127;
  float inv_n = 1.0f / (float)n;
  float mu = bns[c] * inv_n;
  float var = bns[D + c] * inv_n - mu * mu;
  H[idx] = (H[idx] - mu) / sqrtf(var + 1e-5f);
}

// ---------- launch ----------
extern "C" void kernel_launch(void* const* d_in, const int* in_sizes, int n_in,
                              void* d_out, int out_size, void* d_ws, size_t ws_size,
                              hipStream_t stream){
  const float* nf     = (const float*)d_in[0];
  const int*   ei     = (const int*)  d_in[1];
  const float* xprev[2] = { (const float*)d_in[2], (const float*)d_in[3] };
  const float* ts     = (const float*)d_in[4];
  const float* freq   = (const float*)d_in[5];
  const float* phase  = (const float*)d_in[6];
  const float* mergeW = (const float*)d_in[7];
  const float* mergeb = (const float*)d_in[8];
  const float* gatW[2]  = { (const float*)d_in[9],  (const float*)d_in[17] };
  const float* gatAS[2] = { (const float*)d_in[10], (const float*)d_in[18] };
  const float* gatAD[2] = { (const float*)d_in[11], (const float*)d_in[19] };
  const float* gatB[2]  = { (const float*)d_in[12], (const float*)d_in[20] };
  const float* Wih[2]   = { (const float*)d_in[13], (const float*)d_in[21] };
  const float* Whh[2]   = { (const float*)d_in[14], (const float*)d_in[22] };
  const float* bih[2]   = { (const float*)d_in[15], (const float*)d_in[23] };
  const float* bhh[2]   = { (const float*)d_in[16], (const float*)d_in[24] };
  const float* skipW  = (const float*)d_in[25];
  const float* skipb  = (const float*)d_in[26];

  const int n = in_sizes[0] / D;      // 50000
  const int e = in_sizes[1] / 2;      // 640000
  const int etot = e + n;             // 690000
  const size_t nd = (size_t)n * D;

  // workspace carve (4-byte words)
  float* ws   = (float*)d_ws;
  float* x    = ws;                        // nd
  float* xp   = x + nd;                    // nd
  float* gi   = xp + nd;                   // n*3D
  float* gh   = gi + (size_t)n * D3;       // n*3D  (first nd doubles as GAT output hg)
  float* hg   = gh;                        //   alias: hg consumed before gh is written
  float* asrc = gh + (size_t)n * D3;       // n
  float* adst = asrc + n;                  // n
  float* bns  = adst + n;                  // 2*D
  int*   off  = (int*)(bns + 2 * D);       // n+1
  int*   cnt  = off + n + 1;               // n
  int*   bsum = cnt + n;                   // 256
  int*   csr  = bsum + 256;                // etot
  // bf16 transposed weights (ushort)
  unsigned short* WT = (unsigned short*)(csr + etot);
  unsigned short* WTm0 = WT;               // 128*128 each
  unsigned short* WTm1 = WTm0 + 16384;
  unsigned short* WTg0 = WTm1 + 16384;
  unsigned short* WTg1 = WTg0 + 16384;
  unsigned short* WTsk = WTg1 + 16384;
  unsigned short* WTih0 = WTsk + 16384;    // 384*128 each
  unsigned short* WThh0 = WTih0 + 49152;
  unsigned short* WTih1 = WThh0 + 49152;
  unsigned short* WThh1 = WTih1 + 49152;

  float* H1 = (float*)d_out;
  float* H2 = H1 + nd;

  const dim3 b256(256);
  const int nb_nd = (int)((nd + 255) / 256);
  const int nb_e  = (etot + 255) / 256;
  const int nb_n  = (n + 255) / 256;
  const int grows = (n + 63) / 64;         // 782
  const dim3 gm1(1, grows);                // Nc=128
  const dim3 gm3(3, grows);                // Nc=384
  const int nb_w1 = (128 * 128 + 255) / 256;
  const int nb_w3 = (128 * 384 + 255) / 256;

  // ---- CSR build ----
  k_init0<<<nb_n, b256, 0, stream>>>(cnt, bns, n);
  k_hist<<<nb_e, b256, 0, stream>>>(ei, cnt, e, etot);
  k_scan1<<<nb_n, b256, 0, stream>>>(cnt, off, bsum, n);
  k_scan2<<<1, b256, 0, stream>>>(bsum, nb_n);
  k_scan3<<<nb_n, b256, 0, stream>>>(off, bsum, cnt, n, etot);
  k_scatter<<<nb_e, b256, 0, stream>>>(ei, cnt, csr, e, etot);

  // ---- weight transpose+convert to bf16 ----
  k_wcvt<<<nb_w1, b256, 0, stream>>>(mergeW,                 WTm0, 128);
  k_wcvt<<<nb_w1, b256, 0, stream>>>(mergeW + 128 * 128,     WTm1, 128);
  k_wcvt<<<nb_w1, b256, 0, stream>>>(gatW[0], WTg0, 128);
  k_wcvt<<<nb_w1, b256, 0, stream>>>(gatW[1], WTg1, 128);
  k_wcvt<<<nb_w1, b256, 0, stream>>>(skipW,   WTsk, 128);
  k_wcvt<<<nb_w3, b256, 0, stream>>>(Wih[0], WTih0, 384);
  k_wcvt<<<nb_w3, b256, 0, stream>>>(Whh[0], WThh0, 384);
  k_wcvt<<<nb_w3, b256, 0, stream>>>(Wih[1], WTih1, 384);
  k_wcvt<<<nb_w3, b256, 0, stream>>>(Whh[1], WThh1, 384);

  // ---- x = [nf, t_embed] @ mergeW + mergeb  (t_embed staged in gi) ----
  k_timeenc<<<nb_nd, b256, 0, stream>>>(ts, freq, phase, gi, n);
  k_mgemm<false,true ><<<gm1, b256, 0, stream>>>(nf, WTm0, mergeb, x, n, D);
  k_mgemm<true ,false><<<gm1, b256, 0, stream>>>(gi, WTm1, nullptr, x, n, D);

  for (int L = 0; L < 2; ++L){
    const float* gin = (L == 0) ? x : H1;
    float* gout = (L == 0) ? H1 : H2;
    const unsigned short* wtg  = (L == 0) ? WTg0 : WTg1;
    const unsigned short* wtih = (L == 0) ? WTih0 : WTih1;
    const unsigned short* wthh = (L == 0) ? WThh0 : WThh1;
    k_mgemm<false,false><<<gm1, b256, 0, stream>>>(gin, wtg, nullptr, xp, n, D);
    k_attn<<<(int)(((size_t)n * 64 + 255) / 256), b256, 0, stream>>>(xp, gatAS[L], gatAD[L], asrc, adst, n);
    k_gatconv<<<(int)(((size_t)n * 64 + 255) / 256), b256, 0, stream>>>(off, csr, asrc, adst, xp, gatB[L], hg, n);
    k_mgemm<false,true><<<gm3, b256, 0, stream>>>(hg,       wtih, bih[L], gi, n, D3);
    k_mgemm<false,true><<<gm3, b256, 0, stream>>>(xprev[L], wthh, bhh[L], gh, n, D3);
    k_gru<<<nb_nd, b256, 0, stream>>>(gi, gh, xprev[L], gout, (L == 0) ? 1 : 0, n);
  }

  // skip: H2 += x @ skipW + skipb
  k_mgemm<true,true><<<gm1, b256, 0, stream>>>(x, WTsk, skipb, H2, n, D);
  // BatchNorm
  k_bnreduce<<<(n + 127) / 128, b256, 0, stream>>>(H2, bns, n);
  k_bnnorm<<<nb_nd, b256, 0, stream>>>(H2, bns, n);
}

// Round 4
// 710.537 us; speedup vs baseline: 2.0694x; 1.0727x over previous
//
#include <hip/hip_runtime.h>
#include <math.h>

#define D 128
#define D3 384

typedef __attribute__((ext_vector_type(8))) short bf16x8;
typedef __attribute__((ext_vector_type(4))) float f32x4;
typedef __attribute__((ext_vector_type(4))) unsigned int u32x4;

__device__ __forceinline__ float sigmoidf_(float x){ return 1.0f / (1.0f + expf(-x)); }

// round-to-nearest-even f32 -> bf16
__device__ __forceinline__ unsigned short f2bf(float f){
  unsigned u = __float_as_uint(f);
  return (unsigned short)((u + 0x7FFFu + ((u >> 16) & 1u)) >> 16);
}

// ---------- zero small scratch ----------
__global__ __launch_bounds__(256) void k_init0(int* __restrict__ cnt, float* __restrict__ bns, int n){
  int idx = blockIdx.x * 256 + threadIdx.x;
  if (idx < n) cnt[idx] = 0;
  if (idx < 2 * D) bns[idx] = 0.0f;
}

// ---------- time encode ----------
__global__ __launch_bounds__(256) void k_timeenc(const float* __restrict__ ts, const float* __restrict__ freq,
                                                 const float* __restrict__ phase, float* __restrict__ out, int n){
  int idx = blockIdx.x * 256 + threadIdx.x;
  if (idx >= n * D) return;
  int i = idx >> 7, c = idx & 127;
  out[idx] = cosf(ts[i] * freq[c] + phase[c]);
}

// ---------- weight convert+transpose: Wt[c][k] = bf16(W[k][c]), K=128 ----------
__global__ __launch_bounds__(256) void k_wcvt(const float* __restrict__ W, unsigned short* __restrict__ Wt, int Nc){
  int idx = blockIdx.x * 256 + threadIdx.x;
  if (idx >= 128 * Nc) return;
  int k = idx / Nc, c = idx - k * Nc;
  Wt[c * 128 + k] = f2bf(W[idx]);
}

// ---------- bf16 MFMA GEMM: C[M,Nc] (+)= A[M,128] @ Bt^T (+ bias) ----------
// A: f32 [M][128] (converted on the fly, LDS-staged XOR-swizzled).
// Bt: bf16 [Nc][128] pre-transposed, fragments read DIRECT from global (L2-hot).
// BM=64, BN=128, 256 threads = 4 waves; wave w owns cols [w*32, w*32+32).
template<bool ACCUM, bool BIAS>
__global__ __launch_bounds__(256) void k_mgemm(const float* __restrict__ A,
                                               const unsigned short* __restrict__ Bt,
                                               const float* __restrict__ bias,
                                               float* __restrict__ C, int M, int Nc){
  __shared__ __align__(16) unsigned short Alds[64 * 128];   // 16 KB
  const int tid = threadIdx.x;
  const int lane = tid & 63;
  const int w = tid >> 6;
  const int row0 = blockIdx.y * 64;
  const int col0 = blockIdx.x * 128;

  // ---- stage A (f32 -> bf16, XOR-swizzled 16B units) ----
  #pragma unroll
  for (int r = 0; r < 4; ++r){
    int u = r * 256 + tid;
    int row = u >> 4, c16 = u & 15;
    int gr = row0 + row;
    float4 f0 = make_float4(0.f,0.f,0.f,0.f), f1 = f0;
    if (gr < M){
      const float* p = A + (size_t)gr * 128 + c16 * 8;
      f0 = *(const float4*)p;
      f1 = *(const float4*)(p + 4);
    }
    union { unsigned short s[8]; bf16x8 v; } t;
    t.s[0]=f2bf(f0.x); t.s[1]=f2bf(f0.y); t.s[2]=f2bf(f0.z); t.s[3]=f2bf(f0.w);
    t.s[4]=f2bf(f1.x); t.s[5]=f2bf(f1.y); t.s[6]=f2bf(f1.z); t.s[7]=f2bf(f1.w);
    int c16s = c16 ^ (row & 7);
    *(bf16x8*)&Alds[row * 128 + c16s * 8] = t.v;
  }
  __syncthreads();

  // ---- MFMA main: 4 k-steps of 32; B frags direct from global ----
  f32x4 acc[4][2];
  #pragma unroll
  for (int mf = 0; mf < 4; ++mf)
    #pragma unroll
    for (int nf = 0; nf < 2; ++nf)
      #pragma unroll
      for (int i = 0; i < 4; ++i) acc[mf][nf][i] = 0.0f;

  const int l15 = lane & 15, lg = lane >> 4;
  #pragma unroll
  for (int kk = 0; kk < 4; ++kk){
    const int c16 = kk * 4 + lg;
    bf16x8 a[4], b[2];
    #pragma unroll
    for (int nf = 0; nf < 2; ++nf){
      int brow = col0 + w * 32 + nf * 16 + l15;
      b[nf] = *(const bf16x8*)&Bt[(size_t)brow * 128 + c16 * 8];
    }
    #pragma unroll
    for (int mf = 0; mf < 4; ++mf){
      int row = mf * 16 + l15;
      a[mf] = *(bf16x8*)&Alds[row * 128 + ((c16 ^ (row & 7))) * 8];
    }
    #pragma unroll
    for (int mf = 0; mf < 4; ++mf)
      #pragma unroll
      for (int nf = 0; nf < 2; ++nf)
        acc[mf][nf] = __builtin_amdgcn_mfma_f32_16x16x32_bf16(a[mf], b[nf], acc[mf][nf], 0, 0, 0);
  }

  // ---- epilogue ----
  #pragma unroll
  for (int nf = 0; nf < 2; ++nf){
    int c = col0 + w * 32 + nf * 16 + l15;
    float bv = BIAS ? bias[c] : 0.0f;
    #pragma unroll
    for (int mf = 0; mf < 4; ++mf){
      #pragma unroll
      for (int i = 0; i < 4; ++i){
        int rr = row0 + mf * 16 + lg * 4 + i;
        if (rr < M){
          size_t o = (size_t)rr * Nc + c;
          float v = acc[mf][nf][i] + bv;
          if (ACCUM) v += C[o];
          C[o] = v;
        }
      }
    }
  }
}

// ---------- attention coefficients + bf16 row copy for the gather phase ----------
__global__ __launch_bounds__(256) void k_attn(const float* __restrict__ xp, const float* __restrict__ a_s,
                                              const float* __restrict__ a_d, float* __restrict__ asrc,
                                              float* __restrict__ adst, unsigned short* __restrict__ xpb, int n){
  int wave = (blockIdx.x * 256 + threadIdx.x) >> 6;
  int lane = threadIdx.x & 63;
  if (wave >= n) return;
  const float* row = xp + (size_t)wave * D;
  float xa = row[lane], xb = row[lane + 64];
  xpb[(size_t)wave * D + lane]      = f2bf(xa);
  xpb[(size_t)wave * D + 64 + lane] = f2bf(xb);
  float sa = xa * a_s[lane] + xb * a_s[lane + 64];
  float sd = xa * a_d[lane] + xb * a_d[lane + 64];
  #pragma unroll
  for (int off = 32; off > 0; off >>= 1){
    sa += __shfl_down(sa, off);
    sd += __shfl_down(sd, off);
  }
  if (lane == 0){ asrc[wave] = sa; adst[wave] = sd; }
}

// ---------- CSR build ----------
__global__ __launch_bounds__(256) void k_hist(const int* __restrict__ ei, int* __restrict__ cnt, int e, int etot){
  int t = blockIdx.x * 256 + threadIdx.x;
  if (t >= etot) return;
  int d_ = (t < e) ? ei[e + t] : (t - e);
  atomicAdd(&cnt[d_], 1);
}

__global__ __launch_bounds__(256) void k_scan1(const int* __restrict__ cnt, int* __restrict__ off,
                                               int* __restrict__ bsum, int n){
  __shared__ int sm[256];
  int i = blockIdx.x * 256 + threadIdx.x;
  int v = (i < n) ? cnt[i] : 0;
  sm[threadIdx.x] = v;
  __syncthreads();
  #pragma unroll
  for (int d = 1; d < 256; d <<= 1){
    int t = (threadIdx.x >= d) ? sm[threadIdx.x - d] : 0;
    __syncthreads();
    sm[threadIdx.x] += t;
    __syncthreads();
  }
  if (i < n) off[i] = sm[threadIdx.x] - v;
  if (threadIdx.x == 255) bsum[blockIdx.x] = sm[255];
}

__global__ __launch_bounds__(256) void k_scan2(int* __restrict__ bsum, int nb){
  __shared__ int sm[256];
  int v = (threadIdx.x < nb) ? bsum[threadIdx.x] : 0;
  sm[threadIdx.x] = v;
  __syncthreads();
  #pragma unroll
  for (int d = 1; d < 256; d <<= 1){
    int t = (threadIdx.x >= d) ? sm[threadIdx.x - d] : 0;
    __syncthreads();
    sm[threadIdx.x] += t;
    __syncthreads();
  }
  if (threadIdx.x < nb) bsum[threadIdx.x] = sm[threadIdx.x] - v;
}

__global__ __launch_bounds__(256) void k_scan3(int* __restrict__ off, const int* __restrict__ bsum,
                                               int* __restrict__ cursor, int n, int etot){
  int i = blockIdx.x * 256 + threadIdx.x;
  if (i < n){
    int o = off[i] + bsum[blockIdx.x];
    off[i] = o;
    cursor[i] = o;
  }
  if (i == 0) off[n] = etot;
}

__global__ __launch_bounds__(256) void k_scatter(const int* __restrict__ ei, int* __restrict__ cursor,
                                                 int* __restrict__ csr, int e, int etot){
  int t = blockIdx.x * 256 + threadIdx.x;
  if (t >= etot) return;
  int s_, d_;
  if (t < e){ s_ = ei[t]; d_ = ei[e + t]; } else { s_ = d_ = t - e; }
  int pos = atomicAdd(&cursor[d_], 1);
  csr[pos] = s_;
}

// ---------- fused GAT edge phase: one wave per dst node, lane-parallel weights ----------
// Lane l owns channels (2l, 2l+1); gather rows are bf16 (u32 per lane per edge).
__global__ __launch_bounds__(256) void k_gatconv(const int* __restrict__ off, const int* __restrict__ csr,
                                                 const float* __restrict__ asrc, const float* __restrict__ adst,
                                                 const unsigned short* __restrict__ xpb,
                                                 const float* __restrict__ bias,
                                                 float* __restrict__ out, int n){
  int w = (blockIdx.x * 256 + threadIdx.x) >> 6;
  int lane = threadIdx.x & 63;
  if (w >= n) return;
  const int o0 = off[w], o1 = off[w + 1];
  const float ad = adst[w];
  // pass 1: segment max (lane-strided)
  float m = -1e30f;
  for (int j = o0 + lane; j < o1; j += 64){
    float v = asrc[csr[j]] + ad;
    v = (v > 0.0f) ? v : 0.2f * v;
    m = fmaxf(m, v);
  }
  #pragma unroll
  for (int d = 32; d > 0; d >>= 1) m = fmaxf(m, __shfl_xor(m, d));
  // pass 2: chunks of 64 edges. Lane t computes wgt/src for edge base+t (ONE exp
  // per edge, not 64); serial broadcast loop does 2 FMAs per edge via readlane.
  float s = 0.0f, acc0 = 0.0f, acc1 = 0.0f;
  for (int base = o0; base < o1; base += 64){
    int j = base + lane;
    float wgt = 0.0f;
    int src = 0;
    if (j < o1){
      src = csr[j];
      float v = asrc[src] + ad;
      v = (v > 0.0f) ? v : 0.2f * v;
      wgt = expf(v - m);
    }
    s += wgt;
    const int cnt = min(64, o1 - base);
    const int wbits = __float_as_int(wgt);
    for (int t = 0; t < cnt; ++t){
#if defined(__has_builtin) && __has_builtin(__builtin_amdgcn_readlane)
      int sr  = __builtin_amdgcn_readlane(src, t);
      float wg = __int_as_float(__builtin_amdgcn_readlane(wbits, t));
#else
      int sr  = __shfl(src, t);
      float wg = __int_as_float(__shfl(wbits, t));
#endif
      unsigned u = *(const unsigned*)&xpb[(size_t)sr * D + 2 * lane];
      float lo = __uint_as_float(u << 16);
      float hi = __uint_as_float(u & 0xFFFF0000u);
      acc0 = fmaf(wg, lo, acc0);
      acc1 = fmaf(wg, hi, acc1);
    }
  }
  #pragma unroll
  for (int d = 32; d > 0; d >>= 1) s += __shfl_xor(s, d);
  float inv = 1.0f / (s + 1e-16f);
  float2 bv = *(const float2*)&bias[2 * lane];
  float2 o2 = make_float2(acc0 * inv + bv.x, acc1 * inv + bv.y);
  *(float2*)&out[(size_t)w * D + 2 * lane] = o2;
}

// ---------- GRU combine ----------
__global__ __launch_bounds__(256) void k_gru(const float* __restrict__ gi, const float* __restrict__ gh,
                                             const float* __restrict__ hprev, float* __restrict__ out,
                                             int do_relu, int n){
  int idx = blockIdx.x * 256 + threadIdx.x;
  if (idx >= n * D) return;
  int i = idx >> 7, c = idx & 127;
  const float* gir = gi + (size_t)i * D3;
  const float* ghr = gh + (size_t)i * D3;
  float r = sigmoidf_(gir[c] + ghr[c]);
  float z = sigmoidf_(gir[c + D] + ghr[c + D]);
  float nn = tanhf(gir[c + 2*D] + r * ghr[c + 2*D]);
  float h = (1.0f - z) * nn + z * hprev[idx];
  if (do_relu) h = fmaxf(h, 0.0f);
  out[idx] = h;
}

// ---------- BatchNorm ----------
__global__ __launch_bounds__(256) void k_bnreduce(const float* __restrict__ H, float* __restrict__ bns, int n){
  int c = threadIdx.x & 127;
  int half = threadIdx.x >> 7;
  int r0 = blockIdx.x * 128;
  int rend = min(r0 + 128, n);
  float s0 = 0.0f, s1 = 0.0f;
  for (int r = r0 + half; r < rend; r += 2){
    float v = H[(size_t)r * D + c];
    s0 += v; s1 += v * v;
  }
  __shared__ float sm[2][128];
  if (half){ sm[0][c] = s0; sm[1][c] = s1; }
  __syncthreads();
  if (!half){
    s0 += sm[0][c]; s1 += sm[1][c];
    atomicAdd(&bns[c], s0);
    atomicAdd(&bns[D + c], s1);
  }
}

__global__ __launch_bounds__(256) void k_bnnorm(float* __restrict__ H, const float* __restrict__ bns, int n){
  int idx = blockIdx.x * 256 + threadIdx.x;
  if (idx >= n * D) return;
  int c = idx & 127;
  float inv_n = 1.0f / (float)n;
  float mu = bns[c] * inv_n;
  float var = bns[D + c] * inv_n - mu * mu;
  H[idx] = (H[idx] - mu) / sqrtf(var + 1e-5f);
}

// ---------- launch ----------
extern "C" void kernel_launch(void* const* d_in, const int* in_sizes, int n_in,
                              void* d_out, int out_size, void* d_ws, size_t ws_size,
                              hipStream_t stream){
  const float* nf     = (const float*)d_in[0];
  const int*   ei     = (const int*)  d_in[1];
  const float* xprev[2] = { (const float*)d_in[2], (const float*)d_in[3] };
  const float* ts     = (const float*)d_in[4];
  const float* freq   = (const float*)d_in[5];
  const float* phase  = (const float*)d_in[6];
  const float* mergeW = (const float*)d_in[7];
  const float* mergeb = (const float*)d_in[8];
  const float* gatW[2]  = { (const float*)d_in[9],  (const float*)d_in[17] };
  const float* gatAS[2] = { (const float*)d_in[10], (const float*)d_in[18] };
  const float* gatAD[2] = { (const float*)d_in[11], (const float*)d_in[19] };
  const float* gatB[2]  = { (const float*)d_in[12], (const float*)d_in[20] };
  const float* Wih[2]   = { (const float*)d_in[13], (const float*)d_in[21] };
  const float* Whh[2]   = { (const float*)d_in[14], (const float*)d_in[22] };
  const float* bih[2]   = { (const float*)d_in[15], (const float*)d_in[23] };
  const float* bhh[2]   = { (const float*)d_in[16], (const float*)d_in[24] };
  const float* skipW  = (const float*)d_in[25];
  const float* skipb  = (const float*)d_in[26];

  const int n = in_sizes[0] / D;      // 50000
  const int e = in_sizes[1] / 2;      // 640000
  const int etot = e + n;             // 690000
  const size_t nd = (size_t)n * D;

  // workspace carve (4-byte words)
  float* ws   = (float*)d_ws;
  float* x    = ws;                        // nd
  float* xp   = x + nd;                    // nd
  float* gi   = xp + nd;                   // n*3D
  float* gh   = gi + (size_t)n * D3;       // n*3D  (first nd doubles as GAT output hg)
  float* hg   = gh;                        //   alias: hg consumed before gh is written
  float* asrc = gh + (size_t)n * D3;       // n
  float* adst = asrc + n;                  // n
  float* bns  = adst + n;                  // 2*D
  int*   off  = (int*)(bns + 2 * D);       // n+1
  int*   cnt  = off + n + 1;               // n
  int*   bsum = cnt + n;                   // 256
  int*   csr  = bsum + 256;                // etot
  // bf16 transposed weights (ushort)
  unsigned short* WT = (unsigned short*)(csr + etot);
  unsigned short* WTm0 = WT;               // 128*128 each
  unsigned short* WTm1 = WTm0 + 16384;
  unsigned short* WTg0 = WTm1 + 16384;
  unsigned short* WTg1 = WTg0 + 16384;
  unsigned short* WTsk = WTg1 + 16384;
  unsigned short* WTih0 = WTsk + 16384;    // 384*128 each
  unsigned short* WThh0 = WTih0 + 49152;
  unsigned short* WTih1 = WThh0 + 49152;
  unsigned short* WThh1 = WTih1 + 49152;
  unsigned short* xpb = WThh1 + 49152;     // n*128 bf16 gather rows

  float* H1 = (float*)d_out;
  float* H2 = H1 + nd;

  const dim3 b256(256);
  const int nb_nd = (int)((nd + 255) / 256);
  const int nb_e  = (etot + 255) / 256;
  const int nb_n  = (n + 255) / 256;
  const int grows = (n + 63) / 64;         // 782
  const dim3 gm1(1, grows);                // Nc=128
  const dim3 gm3(3, grows);                // Nc=384
  const int nb_w1 = (128 * 128 + 255) / 256;
  const int nb_w3 = (128 * 384 + 255) / 256;
  const int nb_wave = (int)(((size_t)n * 64 + 255) / 256);

  // ---- CSR build ----
  k_init0<<<nb_n, b256, 0, stream>>>(cnt, bns, n);
  k_hist<<<nb_e, b256, 0, stream>>>(ei, cnt, e, etot);
  k_scan1<<<nb_n, b256, 0, stream>>>(cnt, off, bsum, n);
  k_scan2<<<1, b256, 0, stream>>>(bsum, nb_n);
  k_scan3<<<nb_n, b256, 0, stream>>>(off, bsum, cnt, n, etot);
  k_scatter<<<nb_e, b256, 0, stream>>>(ei, cnt, csr, e, etot);

  // ---- weight transpose+convert to bf16 ----
  k_wcvt<<<nb_w1, b256, 0, stream>>>(mergeW,             WTm0, 128);
  k_wcvt<<<nb_w1, b256, 0, stream>>>(mergeW + 128 * 128, WTm1, 128);
  k_wcvt<<<nb_w1, b256, 0, stream>>>(gatW[0], WTg0, 128);
  k_wcvt<<<nb_w1, b256, 0, stream>>>(gatW[1], WTg1, 128);
  k_wcvt<<<nb_w1, b256, 0, stream>>>(skipW,   WTsk, 128);
  k_wcvt<<<nb_w3, b256, 0, stream>>>(Wih[0], WTih0, 384);
  k_wcvt<<<nb_w3, b256, 0, stream>>>(Whh[0], WThh0, 384);
  k_wcvt<<<nb_w3, b256, 0, stream>>>(Wih[1], WTih1, 384);
  k_wcvt<<<nb_w3, b256, 0, stream>>>(Whh[1], WThh1, 384);

  // ---- x = [nf, t_embed] @ mergeW + mergeb  (t_embed staged in gi) ----
  k_timeenc<<<nb_nd, b256, 0, stream>>>(ts, freq, phase, gi, n);
  k_mgemm<false,true ><<<gm1, b256, 0, stream>>>(nf, WTm0, mergeb, x, n, D);
  k_mgemm<true ,false><<<gm1, b256, 0, stream>>>(gi, WTm1, nullptr, x, n, D);

  for (int L = 0; L < 2; ++L){
    const float* gin = (L == 0) ? x : H1;
    float* gout = (L == 0) ? H1 : H2;
    const unsigned short* wtg  = (L == 0) ? WTg0 : WTg1;
    const unsigned short* wtih = (L == 0) ? WTih0 : WTih1;
    const unsigned short* wthh = (L == 0) ? WThh0 : WThh1;
    k_mgemm<false,false><<<gm1, b256, 0, stream>>>(gin, wtg, nullptr, xp, n, D);
    k_attn<<<nb_wave, b256, 0, stream>>>(xp, gatAS[L], gatAD[L], asrc, adst, xpb, n);
    k_gatconv<<<nb_wave, b256, 0, stream>>>(off, csr, asrc, adst, xpb, gatB[L], hg, n);
    k_mgemm<false,true><<<gm3, b256, 0, stream>>>(hg,       wtih, bih[L], gi, n, D3);
    k_mgemm<false,true><<<gm3, b256, 0, stream>>>(xprev[L], wthh, bhh[L], gh, n, D3);
    k_gru<<<nb_nd, b256, 0, stream>>>(gi, gh, xprev[L], gout, (L == 0) ? 1 : 0, n);
  }

  // skip: H2 += x @ skipW + skipb
  k_mgemm<true,true><<<gm1, b256, 0, stream>>>(x, WTsk, skipb, H2, n, D);
  // BatchNorm
  k_bnreduce<<<(n + 127) / 128, b256, 0, stream>>>(H2, bns, n);
  k_bnnorm<<<nb_nd, b256, 0, stream>>>(H2, bns, n);
}

// Round 5
// 590.588 us; speedup vs baseline: 2.4897x; 1.2031x over previous
//
#include <hip/hip_runtime.h>
#include <math.h>

#define D 128
#define D3 384

typedef __attribute__((ext_vector_type(8))) short bf16x8;
typedef __attribute__((ext_vector_type(4))) float f32x4;
typedef __attribute__((ext_vector_type(4))) unsigned int u32x4;

__device__ __forceinline__ float sigmoidf_(float x){ return 1.0f / (1.0f + expf(-x)); }

// round-to-nearest-even f32 -> bf16
__device__ __forceinline__ unsigned short f2bf(float f){
  unsigned u = __float_as_uint(f);
  return (unsigned short)((u + 0x7FFFu + ((u >> 16) & 1u)) >> 16);
}

// ---------- zero small scratch ----------
__global__ __launch_bounds__(256) void k_init0(int* __restrict__ cnt, float* __restrict__ bns, int n){
  int idx = blockIdx.x * 256 + threadIdx.x;
  if (idx < n) cnt[idx] = 0;
  if (idx < 2 * D) bns[idx] = 0.0f;
}

// ---------- weight convert+transpose: Wt[c][k] = bf16(W[k][c]) ----------
__global__ __launch_bounds__(256) void k_wcvt(const float* __restrict__ W, unsigned short* __restrict__ Wt,
                                              int Nc, int K){
  int idx = blockIdx.x * 256 + threadIdx.x;
  if (idx >= K * Nc) return;
  int k = idx / Nc, c = idx - k * Nc;
  Wt[c * K + k] = f2bf(W[idx]);
}

// ---------- merge GEMM: xb = bf16([nf, cos(ts*freq+phase)] @ mergeW + mergeb) ----------
// K=256 (cols 128..255 computed on the fly). BM=64, BN=128, 4 waves.
__global__ __launch_bounds__(256) void k_merge(const float* __restrict__ nf, const float* __restrict__ ts,
                                               const float* __restrict__ freq, const float* __restrict__ phase,
                                               const unsigned short* __restrict__ Bt,  // [128][256]
                                               const float* __restrict__ bias,
                                               unsigned short* __restrict__ xb, int M){
  __shared__ __align__(16) unsigned short Alds[64 * 256];   // 32 KB
  const int tid = threadIdx.x;
  const int lane = tid & 63;
  const int w = tid >> 6;
  const int row0 = blockIdx.y * 64;

  #pragma unroll
  for (int r = 0; r < 8; ++r){
    int u = r * 256 + tid;
    int row = u >> 5, c16 = u & 31;
    int gr = row0 + row;
    union { unsigned short s[8]; bf16x8 v; } t;
    if (gr < M){
      if (c16 < 16){
        const float* p = nf + (size_t)gr * 128 + c16 * 8;
        float4 f0 = *(const float4*)p, f1 = *(const float4*)(p + 4);
        t.s[0]=f2bf(f0.x); t.s[1]=f2bf(f0.y); t.s[2]=f2bf(f0.z); t.s[3]=f2bf(f0.w);
        t.s[4]=f2bf(f1.x); t.s[5]=f2bf(f1.y); t.s[6]=f2bf(f1.z); t.s[7]=f2bf(f1.w);
      } else {
        float tv = ts[gr];
        int ch0 = (c16 - 16) * 8;
        float4 fq0 = *(const float4*)&freq[ch0],  fq1 = *(const float4*)&freq[ch0 + 4];
        float4 ph0 = *(const float4*)&phase[ch0], ph1 = *(const float4*)&phase[ch0 + 4];
        t.s[0]=f2bf(cosf(tv*fq0.x+ph0.x)); t.s[1]=f2bf(cosf(tv*fq0.y+ph0.y));
        t.s[2]=f2bf(cosf(tv*fq0.z+ph0.z)); t.s[3]=f2bf(cosf(tv*fq0.w+ph0.w));
        t.s[4]=f2bf(cosf(tv*fq1.x+ph1.x)); t.s[5]=f2bf(cosf(tv*fq1.y+ph1.y));
        t.s[6]=f2bf(cosf(tv*fq1.z+ph1.z)); t.s[7]=f2bf(cosf(tv*fq1.w+ph1.w));
      }
    } else {
      #pragma unroll
      for (int q = 0; q < 8; ++q) t.s[q] = 0;
    }
    int c16s = c16 ^ (row & 7);
    *(bf16x8*)&Alds[row * 256 + c16s * 8] = t.v;
  }
  __syncthreads();

  f32x4 acc[4][2];
  #pragma unroll
  for (int mf = 0; mf < 4; ++mf)
    #pragma unroll
    for (int nfi = 0; nfi < 2; ++nfi)
      #pragma unroll
      for (int i = 0; i < 4; ++i) acc[mf][nfi][i] = 0.0f;

  const int l15 = lane & 15, lg = lane >> 4;
  #pragma unroll
  for (int kk = 0; kk < 8; ++kk){
    const int c16 = kk * 4 + lg;
    bf16x8 a[4], b[2];
    #pragma unroll
    for (int nfi = 0; nfi < 2; ++nfi){
      int brow = w * 32 + nfi * 16 + l15;
      b[nfi] = *(const bf16x8*)&Bt[(size_t)brow * 256 + c16 * 8];
    }
    #pragma unroll
    for (int mf = 0; mf < 4; ++mf){
      int row = mf * 16 + l15;
      a[mf] = *(bf16x8*)&Alds[row * 256 + ((c16 ^ (row & 7))) * 8];
    }
    #pragma unroll
    for (int mf = 0; mf < 4; ++mf)
      #pragma unroll
      for (int nfi = 0; nfi < 2; ++nfi)
        acc[mf][nfi] = __builtin_amdgcn_mfma_f32_16x16x32_bf16(a[mf], b[nfi], acc[mf][nfi], 0, 0, 0);
  }

  #pragma unroll
  for (int nfi = 0; nfi < 2; ++nfi){
    int c = w * 32 + nfi * 16 + l15;
    float bv = bias[c];
    #pragma unroll
    for (int mf = 0; mf < 4; ++mf)
      #pragma unroll
      for (int i = 0; i < 4; ++i){
        int rr = row0 + mf * 16 + lg * 4 + i;
        if (rr < M) xb[(size_t)rr * 128 + c] = f2bf(acc[mf][nfi][i] + bv);
      }
  }
}

// ---------- bf16 MFMA GEMM: C[M,Nc] (+)= A[M,128] @ Bt^T (+ bias) ----------
// ABF16: A is bf16 (else f32, converted in staging). OUTBF: write bf16 (no ACCUM).
template<bool ABF16, bool OUTBF, bool ACCUM, bool BIAS>
__global__ __launch_bounds__(256) void k_mgemm(const void* __restrict__ Av,
                                               const unsigned short* __restrict__ Bt,
                                               const float* __restrict__ bias,
                                               void* __restrict__ Cv, int M, int Nc){
  __shared__ __align__(16) unsigned short Alds[64 * 128];   // 16 KB
  const int tid = threadIdx.x;
  const int lane = tid & 63;
  const int w = tid >> 6;
  const int row0 = blockIdx.y * 64;
  const int col0 = blockIdx.x * 128;

  #pragma unroll
  for (int r = 0; r < 4; ++r){
    int u = r * 256 + tid;
    int row = u >> 4, c16 = u & 15;
    int gr = row0 + row;
    int c16s = c16 ^ (row & 7);
    if (ABF16){
      u32x4 v = {0,0,0,0};
      if (gr < M) v = *(const u32x4*)((const unsigned short*)Av + (size_t)gr * 128 + c16 * 8);
      *(u32x4*)&Alds[row * 128 + c16s * 8] = v;
    } else {
      float4 f0 = make_float4(0.f,0.f,0.f,0.f), f1 = f0;
      if (gr < M){
        const float* p = (const float*)Av + (size_t)gr * 128 + c16 * 8;
        f0 = *(const float4*)p; f1 = *(const float4*)(p + 4);
      }
      union { unsigned short s[8]; bf16x8 v; } t;
      t.s[0]=f2bf(f0.x); t.s[1]=f2bf(f0.y); t.s[2]=f2bf(f0.z); t.s[3]=f2bf(f0.w);
      t.s[4]=f2bf(f1.x); t.s[5]=f2bf(f1.y); t.s[6]=f2bf(f1.z); t.s[7]=f2bf(f1.w);
      *(bf16x8*)&Alds[row * 128 + c16s * 8] = t.v;
    }
  }
  __syncthreads();

  f32x4 acc[4][2];
  #pragma unroll
  for (int mf = 0; mf < 4; ++mf)
    #pragma unroll
    for (int nfi = 0; nfi < 2; ++nfi)
      #pragma unroll
      for (int i = 0; i < 4; ++i) acc[mf][nfi][i] = 0.0f;

  const int l15 = lane & 15, lg = lane >> 4;
  #pragma unroll
  for (int kk = 0; kk < 4; ++kk){
    const int c16 = kk * 4 + lg;
    bf16x8 a[4], b[2];
    #pragma unroll
    for (int nfi = 0; nfi < 2; ++nfi){
      int brow = col0 + w * 32 + nfi * 16 + l15;
      b[nfi] = *(const bf16x8*)&Bt[(size_t)brow * 128 + c16 * 8];
    }
    #pragma unroll
    for (int mf = 0; mf < 4; ++mf){
      int row = mf * 16 + l15;
      a[mf] = *(bf16x8*)&Alds[row * 128 + ((c16 ^ (row & 7))) * 8];
    }
    #pragma unroll
    for (int mf = 0; mf < 4; ++mf)
      #pragma unroll
      for (int nfi = 0; nfi < 2; ++nfi)
        acc[mf][nfi] = __builtin_amdgcn_mfma_f32_16x16x32_bf16(a[mf], b[nfi], acc[mf][nfi], 0, 0, 0);
  }

  #pragma unroll
  for (int nfi = 0; nfi < 2; ++nfi){
    int c = col0 + w * 32 + nfi * 16 + l15;
    float bv = BIAS ? bias[c] : 0.0f;
    #pragma unroll
    for (int mf = 0; mf < 4; ++mf)
      #pragma unroll
      for (int i = 0; i < 4; ++i){
        int rr = row0 + mf * 16 + lg * 4 + i;
        if (rr < M){
          size_t o = (size_t)rr * Nc + c;
          float v = acc[mf][nfi][i] + bv;
          if (OUTBF){
            ((unsigned short*)Cv)[o] = f2bf(v);
          } else {
            float* C = (float*)Cv;
            if (ACCUM) v += C[o];
            C[o] = v;
          }
        }
      }
  }
}

// ---------- attention coefficients from bf16 xpb ----------
__global__ __launch_bounds__(256) void k_attn(const unsigned short* __restrict__ xpb,
                                              const float* __restrict__ a_s, const float* __restrict__ a_d,
                                              float* __restrict__ asrc, float* __restrict__ adst, int n){
  int wave = (blockIdx.x * 256 + threadIdx.x) >> 6;
  int lane = threadIdx.x & 63;
  if (wave >= n) return;
  unsigned u = *(const unsigned*)&xpb[(size_t)wave * D + 2 * lane];
  float lo = __uint_as_float(u << 16);
  float hi = __uint_as_float(u & 0xFFFF0000u);
  float2 as2 = *(const float2*)&a_s[2 * lane];
  float2 ad2 = *(const float2*)&a_d[2 * lane];
  float sa = lo * as2.x + hi * as2.y;
  float sd = lo * ad2.x + hi * ad2.y;
  #pragma unroll
  for (int off = 32; off > 0; off >>= 1){
    sa += __shfl_down(sa, off);
    sd += __shfl_down(sd, off);
  }
  if (lane == 0){ asrc[wave] = sa; adst[wave] = sd; }
}

// ---------- CSR build ----------
__global__ __launch_bounds__(256) void k_hist(const int* __restrict__ ei, int* __restrict__ cnt, int e, int etot){
  int t = blockIdx.x * 256 + threadIdx.x;
  if (t >= etot) return;
  int d_ = (t < e) ? ei[e + t] : (t - e);
  atomicAdd(&cnt[d_], 1);
}

__global__ __launch_bounds__(256) void k_scan1(const int* __restrict__ cnt, int* __restrict__ off,
                                               int* __restrict__ bsum, int n){
  __shared__ int sm[256];
  int i = blockIdx.x * 256 + threadIdx.x;
  int v = (i < n) ? cnt[i] : 0;
  sm[threadIdx.x] = v;
  __syncthreads();
  #pragma unroll
  for (int d = 1; d < 256; d <<= 1){
    int t = (threadIdx.x >= d) ? sm[threadIdx.x - d] : 0;
    __syncthreads();
    sm[threadIdx.x] += t;
    __syncthreads();
  }
  if (i < n) off[i] = sm[threadIdx.x] - v;
  if (threadIdx.x == 255) bsum[blockIdx.x] = sm[255];
}

__global__ __launch_bounds__(256) void k_scan2(int* __restrict__ bsum, int nb){
  __shared__ int sm[256];
  int v = (threadIdx.x < nb) ? bsum[threadIdx.x] : 0;
  sm[threadIdx.x] = v;
  __syncthreads();
  #pragma unroll
  for (int d = 1; d < 256; d <<= 1){
    int t = (threadIdx.x >= d) ? sm[threadIdx.x - d] : 0;
    __syncthreads();
    sm[threadIdx.x] += t;
    __syncthreads();
  }
  if (threadIdx.x < nb) bsum[threadIdx.x] = sm[threadIdx.x] - v;
}

__global__ __launch_bounds__(256) void k_scan3(int* __restrict__ off, const int* __restrict__ bsum,
                                               int* __restrict__ cursor, int n, int etot){
  int i = blockIdx.x * 256 + threadIdx.x;
  if (i < n){
    int o = off[i] + bsum[blockIdx.x];
    off[i] = o;
    cursor[i] = o;
  }
  if (i == 0) off[n] = etot;
}

__global__ __launch_bounds__(256) void k_scatter(const int* __restrict__ ei, int* __restrict__ cursor,
                                                 int* __restrict__ csr, int e, int etot){
  int t = blockIdx.x * 256 + threadIdx.x;
  if (t >= etot) return;
  int s_, d_;
  if (t < e){ s_ = ei[t]; d_ = ei[e + t]; } else { s_ = d_ = t - e; }
  int pos = atomicAdd(&cursor[d_], 1);
  csr[pos] = s_;
}

// ---------- fused GAT edge phase: one wave per dst node, unroll-8 gather MLP ----------
__global__ __launch_bounds__(256) void k_gatconv(const int* __restrict__ off, const int* __restrict__ csr,
                                                 const float* __restrict__ asrc, const float* __restrict__ adst,
                                                 const unsigned short* __restrict__ xpb,
                                                 const float* __restrict__ bias,
                                                 unsigned short* __restrict__ outb, int n){
  int w = (blockIdx.x * 256 + threadIdx.x) >> 6;
  int lane = threadIdx.x & 63;
  if (w >= n) return;
  const int o0 = off[w], o1 = off[w + 1];
  const float ad = adst[w];
  // pass 1: segment max (lane-strided)
  float m = -1e30f;
  for (int j = o0 + lane; j < o1; j += 64){
    float v = asrc[csr[j]] + ad;
    v = (v > 0.0f) ? v : 0.2f * v;
    m = fmaxf(m, v);
  }
  #pragma unroll
  for (int d = 32; d > 0; d >>= 1) m = fmaxf(m, __shfl_xor(m, d));
  // pass 2: chunks of 64; lane t computes (wgt, src) for edge base+t; broadcast
  // loop unrolled by 8 with batched independent gather loads (MLP).
  float s = 0.0f, acc0 = 0.0f, acc1 = 0.0f;
  for (int base = o0; base < o1; base += 64){
    int j = base + lane;
    float wgt = 0.0f;
    int src = 0;                       // padded lanes: row 0, weight 0 (harmless)
    if (j < o1){
      src = csr[j];
      float v = asrc[src] + ad;
      v = (v > 0.0f) ? v : 0.2f * v;
      wgt = expf(v - m);
    }
    s += wgt;
    const int cnt8 = (min(64, o1 - base) + 7) & ~7;
    const int wbits = __float_as_int(wgt);
    for (int t = 0; t < cnt8; t += 8){
      unsigned uu[8]; float wq[8];
      #pragma unroll
      for (int q = 0; q < 8; ++q){
        int sr = __builtin_amdgcn_readlane(src, t + q);
        wq[q] = __int_as_float(__builtin_amdgcn_readlane(wbits, t + q));
        uu[q] = *(const unsigned*)&xpb[(size_t)sr * D + 2 * lane];
      }
      #pragma unroll
      for (int q = 0; q < 8; ++q){
        acc0 = fmaf(wq[q], __uint_as_float(uu[q] << 16), acc0);
        acc1 = fmaf(wq[q], __uint_as_float(uu[q] & 0xFFFF0000u), acc1);
      }
    }
  }
  #pragma unroll
  for (int d = 32; d > 0; d >>= 1) s += __shfl_xor(s, d);
  float inv = 1.0f / (s + 1e-16f);
  float2 bv = *(const float2*)&bias[2 * lane];
  unsigned pack = ((unsigned)f2bf(acc1 * inv + bv.y) << 16) | f2bf(acc0 * inv + bv.x);
  *(unsigned*)&outb[(size_t)w * D + 2 * lane] = pack;
}

// ---------- fused GRU dual-GEMM: out = GRU(hgb@Wih+bih, xprev@Whh+bhh, xprev) ----------
// BM=32, 256 threads = 4 waves; wave w owns channels [w*32, w*32+32) across all 3 gates.
template<int RELU>
__global__ __launch_bounds__(256) void k_grugemm(const unsigned short* __restrict__ hgb,
                                                 const float* __restrict__ xprev,
                                                 const unsigned short* __restrict__ Wih, // [384][128]
                                                 const unsigned short* __restrict__ Whh, // [384][128]
                                                 const float* __restrict__ bih,
                                                 const float* __restrict__ bhh,
                                                 float* __restrict__ out, int n){
  __shared__ __align__(16) unsigned short A1lds[32 * 128];  // 8 KB (hg)
  __shared__ __align__(16) unsigned short A2lds[32 * 128];  // 8 KB (xprev)
  const int tid = threadIdx.x;
  const int lane = tid & 63;
  const int w = tid >> 6;
  const int row0 = blockIdx.x * 32;

  #pragma unroll
  for (int r = 0; r < 2; ++r){
    int u = r * 256 + tid;
    int row = u >> 4, c16 = u & 15;
    int gr = row0 + row;
    int c16s = c16 ^ (row & 7);
    u32x4 v1 = {0,0,0,0};
    union { unsigned short s[8]; bf16x8 v; } t2;
    #pragma unroll
    for (int q = 0; q < 8; ++q) t2.s[q] = 0;
    if (gr < n){
      v1 = *(const u32x4*)(hgb + (size_t)gr * 128 + c16 * 8);
      const float* p = xprev + (size_t)gr * 128 + c16 * 8;
      float4 f0 = *(const float4*)p, f1 = *(const float4*)(p + 4);
      t2.s[0]=f2bf(f0.x); t2.s[1]=f2bf(f0.y); t2.s[2]=f2bf(f0.z); t2.s[3]=f2bf(f0.w);
      t2.s[4]=f2bf(f1.x); t2.s[5]=f2bf(f1.y); t2.s[6]=f2bf(f1.z); t2.s[7]=f2bf(f1.w);
    }
    *(u32x4*)&A1lds[row * 128 + c16s * 8] = v1;
    *(bf16x8*)&A2lds[row * 128 + c16s * 8] = t2.v;
  }
  __syncthreads();

  f32x4 acc1[2][2][3], acc2[2][2][3];
  #pragma unroll
  for (int mf = 0; mf < 2; ++mf)
    #pragma unroll
    for (int nfi = 0; nfi < 2; ++nfi)
      #pragma unroll
      for (int g = 0; g < 3; ++g)
        #pragma unroll
        for (int i = 0; i < 4; ++i){ acc1[mf][nfi][g][i] = 0.0f; acc2[mf][nfi][g][i] = 0.0f; }

  const int l15 = lane & 15, lg = lane >> 4;
  #pragma unroll
  for (int kk = 0; kk < 4; ++kk){
    const int c16 = kk * 4 + lg;
    bf16x8 a1[2], a2[2];
    #pragma unroll
    for (int mf = 0; mf < 2; ++mf){
      int row = mf * 16 + l15;
      int o = row * 128 + ((c16 ^ (row & 7))) * 8;
      a1[mf] = *(bf16x8*)&A1lds[o];
      a2[mf] = *(bf16x8*)&A2lds[o];
    }
    #pragma unroll
    for (int nfi = 0; nfi < 2; ++nfi)
      #pragma unroll
      for (int g = 0; g < 3; ++g){
        int brow = g * 128 + w * 32 + nfi * 16 + l15;
        bf16x8 b1 = *(const bf16x8*)&Wih[(size_t)brow * 128 + c16 * 8];
        bf16x8 b2 = *(const bf16x8*)&Whh[(size_t)brow * 128 + c16 * 8];
        #pragma unroll
        for (int mf = 0; mf < 2; ++mf){
          acc1[mf][nfi][g] = __builtin_amdgcn_mfma_f32_16x16x32_bf16(a1[mf], b1, acc1[mf][nfi][g], 0, 0, 0);
          acc2[mf][nfi][g] = __builtin_amdgcn_mfma_f32_16x16x32_bf16(a2[mf], b2, acc2[mf][nfi][g], 0, 0, 0);
        }
      }
  }

  #pragma unroll
  for (int nfi = 0; nfi < 2; ++nfi){
    int c = w * 32 + nfi * 16 + l15;
    float bi_r = bih[c], bi_z = bih[c + 128], bi_n = bih[c + 256];
    float bh_r = bhh[c], bh_z = bhh[c + 128], bh_n = bhh[c + 256];
    #pragma unroll
    for (int mf = 0; mf < 2; ++mf)
      #pragma unroll
      for (int i = 0; i < 4; ++i){
        int rr = row0 + mf * 16 + lg * 4 + i;
        if (rr < n){
          float ir = acc1[mf][nfi][0][i] + bi_r, hr = acc2[mf][nfi][0][i] + bh_r;
          float iz = acc1[mf][nfi][1][i] + bi_z, hz = acc2[mf][nfi][1][i] + bh_z;
          float in_ = acc1[mf][nfi][2][i] + bi_n, hn = acc2[mf][nfi][2][i] + bh_n;
          float rg = sigmoidf_(ir + hr);
          float z  = sigmoidf_(iz + hz);
          float nn_ = tanhf(in_ + rg * hn);
          float hp = xprev[(size_t)rr * 128 + c];
          float h = (1.0f - z) * nn_ + z * hp;
          if (RELU) h = fmaxf(h, 0.0f);
          out[(size_t)rr * 128 + c] = h;
        }
      }
  }
}

// ---------- BatchNorm ----------
__global__ __launch_bounds__(256) void k_bnreduce(const float* __restrict__ H, float* __restrict__ bns, int n){
  int c = threadIdx.x & 127;
  int half = threadIdx.x >> 7;
  int r0 = blockIdx.x * 128;
  int rend = min(r0 + 128, n);
  float s0 = 0.0f, s1 = 0.0f;
  for (int r = r0 + half; r < rend; r += 2){
    float v = H[(size_t)r * D + c];
    s0 += v; s1 += v * v;
  }
  __shared__ float sm[2][128];
  if (half){ sm[0][c] = s0; sm[1][c] = s1; }
  __syncthreads();
  if (!half){
    s0 += sm[0][c]; s1 += sm[1][c];
    atomicAdd(&bns[c], s0);
    atomicAdd(&bns[D + c], s1);
  }
}

__global__ __launch_bounds__(256) void k_bnnorm(float* __restrict__ H, const float* __restrict__ bns, int n){
  int idx = blockIdx.x * 256 + threadIdx.x;
  if (idx >= n * D) return;
  int c = idx & 127;
  float inv_n = 1.0f / (float)n;
  float mu = bns[c] * inv_n;
  float var = bns[D + c] * inv_n - mu * mu;
  H[idx] = (H[idx] - mu) / sqrtf(var + 1e-5f);
}

// ---------- launch ----------
extern "C" void kernel_launch(void* const* d_in, const int* in_sizes, int n_in,
                              void* d_out, int out_size, void* d_ws, size_t ws_size,
                              hipStream_t stream){
  const float* nf     = (const float*)d_in[0];
  const int*   ei     = (const int*)  d_in[1];
  const float* xprev[2] = { (const float*)d_in[2], (const float*)d_in[3] };
  const float* ts     = (const float*)d_in[4];
  const float* freq   = (const float*)d_in[5];
  const float* phase  = (const float*)d_in[6];
  const float* mergeW = (const float*)d_in[7];
  const float* mergeb = (const float*)d_in[8];
  const float* gatW[2]  = { (const float*)d_in[9],  (const float*)d_in[17] };
  const float* gatAS[2] = { (const float*)d_in[10], (const float*)d_in[18] };
  const float* gatAD[2] = { (const float*)d_in[11], (const float*)d_in[19] };
  const float* gatB[2]  = { (const float*)d_in[12], (const float*)d_in[20] };
  const float* Wih[2]   = { (const float*)d_in[13], (const float*)d_in[21] };
  const float* Whh[2]   = { (const float*)d_in[14], (const float*)d_in[22] };
  const float* bih[2]   = { (const float*)d_in[15], (const float*)d_in[23] };
  const float* bhh[2]   = { (const float*)d_in[16], (const float*)d_in[24] };
  const float* skipW  = (const float*)d_in[25];
  const float* skipb  = (const float*)d_in[26];

  const int n = in_sizes[0] / D;      // 50000
  const int e = in_sizes[1] / 2;      // 640000
  const int etot = e + n;             // 690000
  const size_t nd = (size_t)n * D;

  // workspace carve (4-byte words)
  float* ws   = (float*)d_ws;
  float* asrc = ws;                        // n
  float* adst = asrc + n;                  // n
  float* bns  = adst + n;                  // 2*D
  int*   off  = (int*)(bns + 2 * D);       // n+1
  int*   cnt  = off + n + 1;               // n
  int*   bsum = cnt + n;                   // 256
  int*   csr  = bsum + 256;                // etot
  unsigned short* WTm  = (unsigned short*)(csr + etot);  // 128 x 256
  unsigned short* WTg0 = WTm  + 32768;     // 128 x 128 each
  unsigned short* WTg1 = WTg0 + 16384;
  unsigned short* WTsk = WTg1 + 16384;
  unsigned short* WTih0 = WTsk + 16384;    // 384 x 128 each
  unsigned short* WThh0 = WTih0 + 49152;
  unsigned short* WTih1 = WThh0 + 49152;
  unsigned short* WThh1 = WTih1 + 49152;
  unsigned short* xb   = WThh1 + 49152;    // n*128 bf16
  unsigned short* xpb  = xb  + nd;         // n*128 bf16
  unsigned short* hgb  = xpb + nd;         // n*128 bf16

  float* H1 = (float*)d_out;
  float* H2 = H1 + nd;

  const dim3 b256(256);
  const int nb_nd = (int)((nd + 255) / 256);
  const int nb_e  = (etot + 255) / 256;
  const int nb_n  = (n + 255) / 256;
  const int grows = (n + 63) / 64;         // 782
  const dim3 gm1(1, grows);                // Nc=128 GEMMs
  const int gru_blocks = (n + 31) / 32;    // 1563
  const int nb_wave = (int)(((size_t)n * 64 + 255) / 256);

  // ---- CSR build ----
  k_init0<<<nb_n, b256, 0, stream>>>(cnt, bns, n);
  k_hist<<<nb_e, b256, 0, stream>>>(ei, cnt, e, etot);
  k_scan1<<<nb_n, b256, 0, stream>>>(cnt, off, bsum, n);
  k_scan2<<<1, b256, 0, stream>>>(bsum, nb_n);
  k_scan3<<<nb_n, b256, 0, stream>>>(off, bsum, cnt, n, etot);
  k_scatter<<<nb_e, b256, 0, stream>>>(ei, cnt, csr, e, etot);

  // ---- weight transpose+convert to bf16 ----
  k_wcvt<<<128, b256, 0, stream>>>(mergeW, WTm, 128, 256);
  k_wcvt<<< 64, b256, 0, stream>>>(gatW[0], WTg0, 128, 128);
  k_wcvt<<< 64, b256, 0, stream>>>(gatW[1], WTg1, 128, 128);
  k_wcvt<<< 64, b256, 0, stream>>>(skipW,   WTsk, 128, 128);
  k_wcvt<<<192, b256, 0, stream>>>(Wih[0], WTih0, 384, 128);
  k_wcvt<<<192, b256, 0, stream>>>(Whh[0], WThh0, 384, 128);
  k_wcvt<<<192, b256, 0, stream>>>(Wih[1], WTih1, 384, 128);
  k_wcvt<<<192, b256, 0, stream>>>(Whh[1], WThh1, 384, 128);

  // ---- merge: xb = bf16([nf, cos] @ mergeW + mergeb) ----
  k_merge<<<gm1, b256, 0, stream>>>(nf, ts, freq, phase, WTm, mergeb, xb, n);

  for (int L = 0; L < 2; ++L){
    float* gout = (L == 0) ? H1 : H2;
    const unsigned short* wtg  = (L == 0) ? WTg0 : WTg1;
    const unsigned short* wtih = (L == 0) ? WTih0 : WTih1;
    const unsigned short* wthh = (L == 0) ? WThh0 : WThh1;
    if (L == 0)
      k_mgemm<true , true, false, false><<<gm1, b256, 0, stream>>>(xb, wtg, nullptr, xpb, n, D);
    else
      k_mgemm<false, true, false, false><<<gm1, b256, 0, stream>>>(H1, wtg, nullptr, xpb, n, D);
    k_attn<<<nb_wave, b256, 0, stream>>>(xpb, gatAS[L], gatAD[L], asrc, adst, n);
    k_gatconv<<<nb_wave, b256, 0, stream>>>(off, csr, asrc, adst, xpb, gatB[L], hgb, n);
    if (L == 0)
      k_grugemm<1><<<gru_blocks, b256, 0, stream>>>(hgb, xprev[0], wtih, wthh, bih[0], bhh[0], gout, n);
    else
      k_grugemm<0><<<gru_blocks, b256, 0, stream>>>(hgb, xprev[1], wtih, wthh, bih[1], bhh[1], gout, n);
  }

  // skip: H2 += xb @ skipW + skipb
  k_mgemm<true, false, true, true><<<gm1, b256, 0, stream>>>(xb, WTsk, skipb, H2, n, D);
  // BatchNorm
  k_bnreduce<<<(n + 127) / 128, b256, 0, stream>>>(H2, bns, n);
  k_bnnorm<<<nb_nd, b256, 0, stream>>>(H2, bns, n);
}

// Round 6
// 507.700 us; speedup vs baseline: 2.8962x; 1.1633x over previous
//
#include <hip/hip_runtime.h>
#include <math.h>

#define D 128
#define D3 384

typedef __attribute__((ext_vector_type(8))) short bf16x8;
typedef __attribute__((ext_vector_type(4))) float f32x4;
typedef __attribute__((ext_vector_type(4))) unsigned int u32x4;

// fast transcendentals (native v_exp_f32 / v_rcp_f32 / v_cos_f32)
__device__ __forceinline__ float fsigmoid(float x){
  return __builtin_amdgcn_rcpf(1.0f + __expf(-x));
}
__device__ __forceinline__ float ftanh(float x){
  float e = __expf(2.0f * x);
  return 1.0f - 2.0f * __builtin_amdgcn_rcpf(e + 1.0f);
}

// round-to-nearest-even f32 -> bf16
__device__ __forceinline__ unsigned short f2bf(float f){
  unsigned u = __float_as_uint(f);
  return (unsigned short)((u + 0x7FFFu + ((u >> 16) & 1u)) >> 16);
}

// ---------- zero small scratch ----------
__global__ __launch_bounds__(256) void k_init0(int* __restrict__ cnt, float* __restrict__ bns, int n){
  int idx = blockIdx.x * 256 + threadIdx.x;
  if (idx < n) cnt[idx] = 0;
  if (idx < 2 * D) bns[idx] = 0.0f;
}

// ---------- weight convert+transpose: Wt[c][k] = bf16(W[k][c]) ----------
__global__ __launch_bounds__(256) void k_wcvt(const float* __restrict__ W, unsigned short* __restrict__ Wt,
                                              int Nc, int K){
  int idx = blockIdx.x * 256 + threadIdx.x;
  if (idx >= K * Nc) return;
  int k = idx / Nc, c = idx - k * Nc;
  Wt[c * K + k] = f2bf(W[idx]);
}

// ---------- merge GEMM: xb = bf16([nf, cos(ts*freq+phase)] @ mergeW + mergeb) ----------
__global__ __launch_bounds__(256) void k_merge(const float* __restrict__ nf, const float* __restrict__ ts,
                                               const float* __restrict__ freq, const float* __restrict__ phase,
                                               const unsigned short* __restrict__ Bt,  // [128][256]
                                               const float* __restrict__ bias,
                                               unsigned short* __restrict__ xb, int M){
  __shared__ __align__(16) unsigned short Alds[64 * 256];   // 32 KB
  const int tid = threadIdx.x;
  const int lane = tid & 63;
  const int w = tid >> 6;
  const int row0 = blockIdx.y * 64;

  #pragma unroll
  for (int r = 0; r < 8; ++r){
    int u = r * 256 + tid;
    int row = u >> 5, c16 = u & 31;
    int gr = row0 + row;
    union { unsigned short s[8]; bf16x8 v; } t;
    if (gr < M){
      if (c16 < 16){
        const float* p = nf + (size_t)gr * 128 + c16 * 8;
        float4 f0 = *(const float4*)p, f1 = *(const float4*)(p + 4);
        t.s[0]=f2bf(f0.x); t.s[1]=f2bf(f0.y); t.s[2]=f2bf(f0.z); t.s[3]=f2bf(f0.w);
        t.s[4]=f2bf(f1.x); t.s[5]=f2bf(f1.y); t.s[6]=f2bf(f1.z); t.s[7]=f2bf(f1.w);
      } else {
        float tv = ts[gr];
        int ch0 = (c16 - 16) * 8;
        float4 fq0 = *(const float4*)&freq[ch0],  fq1 = *(const float4*)&freq[ch0 + 4];
        float4 ph0 = *(const float4*)&phase[ch0], ph1 = *(const float4*)&phase[ch0 + 4];
        t.s[0]=f2bf(__cosf(tv*fq0.x+ph0.x)); t.s[1]=f2bf(__cosf(tv*fq0.y+ph0.y));
        t.s[2]=f2bf(__cosf(tv*fq0.z+ph0.z)); t.s[3]=f2bf(__cosf(tv*fq0.w+ph0.w));
        t.s[4]=f2bf(__cosf(tv*fq1.x+ph1.x)); t.s[5]=f2bf(__cosf(tv*fq1.y+ph1.y));
        t.s[6]=f2bf(__cosf(tv*fq1.z+ph1.z)); t.s[7]=f2bf(__cosf(tv*fq1.w+ph1.w));
      }
    } else {
      #pragma unroll
      for (int q = 0; q < 8; ++q) t.s[q] = 0;
    }
    int c16s = c16 ^ (row & 7);
    *(bf16x8*)&Alds[row * 256 + c16s * 8] = t.v;
  }
  __syncthreads();

  f32x4 acc[4][2];
  #pragma unroll
  for (int mf = 0; mf < 4; ++mf)
    #pragma unroll
    for (int nfi = 0; nfi < 2; ++nfi)
      #pragma unroll
      for (int i = 0; i < 4; ++i) acc[mf][nfi][i] = 0.0f;

  const int l15 = lane & 15, lg = lane >> 4;
  #pragma unroll
  for (int kk = 0; kk < 8; ++kk){
    const int c16 = kk * 4 + lg;
    bf16x8 a[4], b[2];
    #pragma unroll
    for (int nfi = 0; nfi < 2; ++nfi){
      int brow = w * 32 + nfi * 16 + l15;
      b[nfi] = *(const bf16x8*)&Bt[(size_t)brow * 256 + c16 * 8];
    }
    #pragma unroll
    for (int mf = 0; mf < 4; ++mf){
      int row = mf * 16 + l15;
      a[mf] = *(bf16x8*)&Alds[row * 256 + ((c16 ^ (row & 7))) * 8];
    }
    #pragma unroll
    for (int mf = 0; mf < 4; ++mf)
      #pragma unroll
      for (int nfi = 0; nfi < 2; ++nfi)
        acc[mf][nfi] = __builtin_amdgcn_mfma_f32_16x16x32_bf16(a[mf], b[nfi], acc[mf][nfi], 0, 0, 0);
  }

  #pragma unroll
  for (int nfi = 0; nfi < 2; ++nfi){
    int c = w * 32 + nfi * 16 + l15;
    float bv = bias[c];
    #pragma unroll
    for (int mf = 0; mf < 4; ++mf)
      #pragma unroll
      for (int i = 0; i < 4; ++i){
        int rr = row0 + mf * 16 + lg * 4 + i;
        if (rr < M) xb[(size_t)rr * 128 + c] = f2bf(acc[mf][nfi][i] + bv);
      }
  }
}

// ---------- bf16 MFMA GEMM: C[M,Nc] (+)= A[M,128] @ Bt^T (+ bias) ----------
template<bool ABF16, bool OUTBF, bool ACCUM, bool BIAS>
__global__ __launch_bounds__(256) void k_mgemm(const void* __restrict__ Av,
                                               const unsigned short* __restrict__ Bt,
                                               const float* __restrict__ bias,
                                               void* __restrict__ Cv, int M, int Nc){
  __shared__ __align__(16) unsigned short Alds[64 * 128];   // 16 KB
  const int tid = threadIdx.x;
  const int lane = tid & 63;
  const int w = tid >> 6;
  const int row0 = blockIdx.y * 64;
  const int col0 = blockIdx.x * 128;

  #pragma unroll
  for (int r = 0; r < 4; ++r){
    int u = r * 256 + tid;
    int row = u >> 4, c16 = u & 15;
    int gr = row0 + row;
    int c16s = c16 ^ (row & 7);
    if (ABF16){
      u32x4 v = {0,0,0,0};
      if (gr < M) v = *(const u32x4*)((const unsigned short*)Av + (size_t)gr * 128 + c16 * 8);
      *(u32x4*)&Alds[row * 128 + c16s * 8] = v;
    } else {
      float4 f0 = make_float4(0.f,0.f,0.f,0.f), f1 = f0;
      if (gr < M){
        const float* p = (const float*)Av + (size_t)gr * 128 + c16 * 8;
        f0 = *(const float4*)p; f1 = *(const float4*)(p + 4);
      }
      union { unsigned short s[8]; bf16x8 v; } t;
      t.s[0]=f2bf(f0.x); t.s[1]=f2bf(f0.y); t.s[2]=f2bf(f0.z); t.s[3]=f2bf(f0.w);
      t.s[4]=f2bf(f1.x); t.s[5]=f2bf(f1.y); t.s[6]=f2bf(f1.z); t.s[7]=f2bf(f1.w);
      *(bf16x8*)&Alds[row * 128 + c16s * 8] = t.v;
    }
  }
  __syncthreads();

  f32x4 acc[4][2];
  #pragma unroll
  for (int mf = 0; mf < 4; ++mf)
    #pragma unroll
    for (int nfi = 0; nfi < 2; ++nfi)
      #pragma unroll
      for (int i = 0; i < 4; ++i) acc[mf][nfi][i] = 0.0f;

  const int l15 = lane & 15, lg = lane >> 4;
  #pragma unroll
  for (int kk = 0; kk < 4; ++kk){
    const int c16 = kk * 4 + lg;
    bf16x8 a[4], b[2];
    #pragma unroll
    for (int nfi = 0; nfi < 2; ++nfi){
      int brow = col0 + w * 32 + nfi * 16 + l15;
      b[nfi] = *(const bf16x8*)&Bt[(size_t)brow * 128 + c16 * 8];
    }
    #pragma unroll
    for (int mf = 0; mf < 4; ++mf){
      int row = mf * 16 + l15;
      a[mf] = *(bf16x8*)&Alds[row * 128 + ((c16 ^ (row & 7))) * 8];
    }
    #pragma unroll
    for (int mf = 0; mf < 4; ++mf)
      #pragma unroll
      for (int nfi = 0; nfi < 2; ++nfi)
        acc[mf][nfi] = __builtin_amdgcn_mfma_f32_16x16x32_bf16(a[mf], b[nfi], acc[mf][nfi], 0, 0, 0);
  }

  #pragma unroll
  for (int nfi = 0; nfi < 2; ++nfi){
    int c = col0 + w * 32 + nfi * 16 + l15;
    float bv = BIAS ? bias[c] : 0.0f;
    #pragma unroll
    for (int mf = 0; mf < 4; ++mf)
      #pragma unroll
      for (int i = 0; i < 4; ++i){
        int rr = row0 + mf * 16 + lg * 4 + i;
        if (rr < M){
          size_t o = (size_t)rr * Nc + c;
          float v = acc[mf][nfi][i] + bv;
          if (OUTBF){
            ((unsigned short*)Cv)[o] = f2bf(v);
          } else {
            float* C = (float*)Cv;
            if (ACCUM) v += C[o];
            C[o] = v;
          }
        }
      }
  }
}

// ---------- attention coefficients from bf16 xpb ----------
__global__ __launch_bounds__(256) void k_attn(const unsigned short* __restrict__ xpb,
                                              const float* __restrict__ a_s, const float* __restrict__ a_d,
                                              float* __restrict__ asrc, float* __restrict__ adst, int n){
  int wave = (blockIdx.x * 256 + threadIdx.x) >> 6;
  int lane = threadIdx.x & 63;
  if (wave >= n) return;
  unsigned u = *(const unsigned*)&xpb[(size_t)wave * D + 2 * lane];
  float lo = __uint_as_float(u << 16);
  float hi = __uint_as_float(u & 0xFFFF0000u);
  float2 as2 = *(const float2*)&a_s[2 * lane];
  float2 ad2 = *(const float2*)&a_d[2 * lane];
  float sa = lo * as2.x + hi * as2.y;
  float sd = lo * ad2.x + hi * ad2.y;
  #pragma unroll
  for (int off = 32; off > 0; off >>= 1){
    sa += __shfl_down(sa, off);
    sd += __shfl_down(sd, off);
  }
  if (lane == 0){ asrc[wave] = sa; adst[wave] = sd; }
}

// ---------- CSR build ----------
__global__ __launch_bounds__(256) void k_hist(const int* __restrict__ ei, int* __restrict__ cnt, int e, int etot){
  int t = blockIdx.x * 256 + threadIdx.x;
  if (t >= etot) return;
  int d_ = (t < e) ? ei[e + t] : (t - e);
  atomicAdd(&cnt[d_], 1);
}

__global__ __launch_bounds__(256) void k_scan1(const int* __restrict__ cnt, int* __restrict__ off,
                                               int* __restrict__ bsum, int n){
  __shared__ int sm[256];
  int i = blockIdx.x * 256 + threadIdx.x;
  int v = (i < n) ? cnt[i] : 0;
  sm[threadIdx.x] = v;
  __syncthreads();
  #pragma unroll
  for (int d = 1; d < 256; d <<= 1){
    int t = (threadIdx.x >= d) ? sm[threadIdx.x - d] : 0;
    __syncthreads();
    sm[threadIdx.x] += t;
    __syncthreads();
  }
  if (i < n) off[i] = sm[threadIdx.x] - v;
  if (threadIdx.x == 255) bsum[blockIdx.x] = sm[255];
}

__global__ __launch_bounds__(256) void k_scan2(int* __restrict__ bsum, int nb){
  __shared__ int sm[256];
  int v = (threadIdx.x < nb) ? bsum[threadIdx.x] : 0;
  sm[threadIdx.x] = v;
  __syncthreads();
  #pragma unroll
  for (int d = 1; d < 256; d <<= 1){
    int t = (threadIdx.x >= d) ? sm[threadIdx.x - d] : 0;
    __syncthreads();
    sm[threadIdx.x] += t;
    __syncthreads();
  }
  if (threadIdx.x < nb) bsum[threadIdx.x] = sm[threadIdx.x] - v;
}

__global__ __launch_bounds__(256) void k_scan3(int* __restrict__ off, const int* __restrict__ bsum,
                                               int* __restrict__ cursor, int n, int etot){
  int i = blockIdx.x * 256 + threadIdx.x;
  if (i < n){
    int o = off[i] + bsum[blockIdx.x];
    off[i] = o;
    cursor[i] = o;
  }
  if (i == 0) off[n] = etot;
}

__global__ __launch_bounds__(256) void k_scatter(const int* __restrict__ ei, int* __restrict__ cursor,
                                                 int* __restrict__ csr, int e, int etot){
  int t = blockIdx.x * 256 + threadIdx.x;
  if (t >= etot) return;
  int s_, d_;
  if (t < e){ s_ = ei[t]; d_ = ei[e + t]; } else { s_ = d_ = t - e; }
  int pos = atomicAdd(&cursor[d_], 1);
  csr[pos] = s_;
}

// ---------- fused GAT edge phase: one wave per dst node, unroll-8 gather MLP ----------
__global__ __launch_bounds__(256) void k_gatconv(const int* __restrict__ off, const int* __restrict__ csr,
                                                 const float* __restrict__ asrc, const float* __restrict__ adst,
                                                 const unsigned short* __restrict__ xpb,
                                                 const float* __restrict__ bias,
                                                 unsigned short* __restrict__ outb, int n){
  int w = (blockIdx.x * 256 + threadIdx.x) >> 6;
  int lane = threadIdx.x & 63;
  if (w >= n) return;
  const int o0 = off[w], o1 = off[w + 1];
  const float ad = adst[w];
  float m = -1e30f;
  for (int j = o0 + lane; j < o1; j += 64){
    float v = asrc[csr[j]] + ad;
    v = (v > 0.0f) ? v : 0.2f * v;
    m = fmaxf(m, v);
  }
  #pragma unroll
  for (int d = 32; d > 0; d >>= 1) m = fmaxf(m, __shfl_xor(m, d));
  float s = 0.0f, acc0 = 0.0f, acc1 = 0.0f;
  for (int base = o0; base < o1; base += 64){
    int j = base + lane;
    float wgt = 0.0f;
    int src = 0;
    if (j < o1){
      src = csr[j];
      float v = asrc[src] + ad;
      v = (v > 0.0f) ? v : 0.2f * v;
      wgt = __expf(v - m);
    }
    s += wgt;
    const int cnt8 = (min(64, o1 - base) + 7) & ~7;
    const int wbits = __float_as_int(wgt);
    for (int t = 0; t < cnt8; t += 8){
      unsigned uu[8]; float wq[8];
      #pragma unroll
      for (int q = 0; q < 8; ++q){
        int sr = __builtin_amdgcn_readlane(src, t + q);
        wq[q] = __int_as_float(__builtin_amdgcn_readlane(wbits, t + q));
        uu[q] = *(const unsigned*)&xpb[(size_t)sr * D + 2 * lane];
      }
      #pragma unroll
      for (int q = 0; q < 8; ++q){
        acc0 = fmaf(wq[q], __uint_as_float(uu[q] << 16), acc0);
        acc1 = fmaf(wq[q], __uint_as_float(uu[q] & 0xFFFF0000u), acc1);
      }
    }
  }
  #pragma unroll
  for (int d = 32; d > 0; d >>= 1) s += __shfl_xor(s, d);
  float inv = 1.0f / (s + 1e-16f);
  float2 bv = *(const float2*)&bias[2 * lane];
  unsigned pack = ((unsigned)f2bf(acc1 * inv + bv.y) << 16) | f2bf(acc0 * inv + bv.x);
  *(unsigned*)&outb[(size_t)w * D + 2 * lane] = pack;
}

// ---------- fused GRU dual-GEMM v2: BM=64, 8 waves, wave owns 16 H-cols ----------
// r,z gates: gi and gh MFMAs chain into ONE accumulator (only the sum is needed);
// n gate keeps in_/hn separate (tanh(in + r*hn)). 96 MFMA : 24 B-loads per wave.
template<int RELU>
__global__ __launch_bounds__(512) void k_grugemm(const unsigned short* __restrict__ hgb,
                                                 const float* __restrict__ xprev,
                                                 const unsigned short* __restrict__ Wih, // [384][128] bf16
                                                 const unsigned short* __restrict__ Whh, // [384][128] bf16
                                                 const float* __restrict__ bih,
                                                 const float* __restrict__ bhh,
                                                 float* __restrict__ out, int n){
  __shared__ __align__(16) unsigned short A1lds[64 * 128];  // 16 KB (hg, bf16)
  __shared__ __align__(16) unsigned short A2lds[64 * 128];  // 16 KB (xprev->bf16)
  const int tid = threadIdx.x;
  const int lane = tid & 63;
  const int w = tid >> 6;               // 0..7
  const int row0 = blockIdx.x * 64;

  #pragma unroll
  for (int r = 0; r < 2; ++r){
    int u = r * 512 + tid;
    int row = u >> 4, c16 = u & 15;
    int gr = row0 + row;
    int c16s = c16 ^ (row & 7);
    u32x4 v1 = {0,0,0,0};
    union { unsigned short s[8]; bf16x8 v; } t2;
    #pragma unroll
    for (int q = 0; q < 8; ++q) t2.s[q] = 0;
    if (gr < n){
      v1 = *(const u32x4*)(hgb + (size_t)gr * 128 + c16 * 8);
      const float* p = xprev + (size_t)gr * 128 + c16 * 8;
      float4 f0 = *(const float4*)p, f1 = *(const float4*)(p + 4);
      t2.s[0]=f2bf(f0.x); t2.s[1]=f2bf(f0.y); t2.s[2]=f2bf(f0.z); t2.s[3]=f2bf(f0.w);
      t2.s[4]=f2bf(f1.x); t2.s[5]=f2bf(f1.y); t2.s[6]=f2bf(f1.z); t2.s[7]=f2bf(f1.w);
    }
    *(u32x4*)&A1lds[row * 128 + c16s * 8] = v1;
    *(bf16x8*)&A2lds[row * 128 + c16s * 8] = t2.v;
  }
  __syncthreads();

  f32x4 accR[4], accZ[4], accN[4], accH[4];
  #pragma unroll
  for (int mf = 0; mf < 4; ++mf)
    #pragma unroll
    for (int i = 0; i < 4; ++i){ accR[mf][i]=0.f; accZ[mf][i]=0.f; accN[mf][i]=0.f; accH[mf][i]=0.f; }

  const int l15 = lane & 15, lg = lane >> 4;
  const int cw = w * 16 + l15;          // this lane's output column (0..127)
  #pragma unroll
  for (int kk = 0; kk < 4; ++kk){
    const int c16 = kk * 4 + lg;
    bf16x8 a1[4], a2[4];
    #pragma unroll
    for (int mf = 0; mf < 4; ++mf){
      int row = mf * 16 + l15;
      int o = row * 128 + ((c16 ^ (row & 7))) * 8;
      a1[mf] = *(bf16x8*)&A1lds[o];
      a2[mf] = *(bf16x8*)&A2lds[o];
    }
    const size_t ko = (size_t)c16 * 8;
    bf16x8 bir = *(const bf16x8*)&Wih[(size_t)(cw      ) * 128 + ko];
    bf16x8 bhr = *(const bf16x8*)&Whh[(size_t)(cw      ) * 128 + ko];
    bf16x8 biz = *(const bf16x8*)&Wih[(size_t)(cw + 128) * 128 + ko];
    bf16x8 bhz = *(const bf16x8*)&Whh[(size_t)(cw + 128) * 128 + ko];
    bf16x8 bin = *(const bf16x8*)&Wih[(size_t)(cw + 256) * 128 + ko];
    bf16x8 bhn = *(const bf16x8*)&Whh[(size_t)(cw + 256) * 128 + ko];
    #pragma unroll
    for (int mf = 0; mf < 4; ++mf){
      accR[mf] = __builtin_amdgcn_mfma_f32_16x16x32_bf16(a1[mf], bir, accR[mf], 0, 0, 0);
      accR[mf] = __builtin_amdgcn_mfma_f32_16x16x32_bf16(a2[mf], bhr, accR[mf], 0, 0, 0);
      accZ[mf] = __builtin_amdgcn_mfma_f32_16x16x32_bf16(a1[mf], biz, accZ[mf], 0, 0, 0);
      accZ[mf] = __builtin_amdgcn_mfma_f32_16x16x32_bf16(a2[mf], bhz, accZ[mf], 0, 0, 0);
      accN[mf] = __builtin_amdgcn_mfma_f32_16x16x32_bf16(a1[mf], bin, accN[mf], 0, 0, 0);
      accH[mf] = __builtin_amdgcn_mfma_f32_16x16x32_bf16(a2[mf], bhn, accH[mf], 0, 0, 0);
    }
  }

  const float sbR = bih[cw] + bhh[cw];
  const float sbZ = bih[cw + 128] + bhh[cw + 128];
  const float biN = bih[cw + 256], bhN = bhh[cw + 256];
  #pragma unroll
  for (int mf = 0; mf < 4; ++mf)
    #pragma unroll
    for (int i = 0; i < 4; ++i){
      int rr = row0 + mf * 16 + lg * 4 + i;
      if (rr < n){
        float r  = fsigmoid(accR[mf][i] + sbR);
        float z  = fsigmoid(accZ[mf][i] + sbZ);
        float nn = ftanh(accN[mf][i] + biN + r * (accH[mf][i] + bhN));
        float hp = xprev[(size_t)rr * 128 + cw];
        float h = (1.0f - z) * nn + z * hp;
        if (RELU) h = fmaxf(h, 0.0f);
        out[(size_t)rr * 128 + cw] = h;
      }
    }
}

// ---------- BatchNorm ----------
__global__ __launch_bounds__(256) void k_bnreduce(const float* __restrict__ H, float* __restrict__ bns, int n){
  int c = threadIdx.x & 127;
  int half = threadIdx.x >> 7;
  int r0 = blockIdx.x * 128;
  int rend = min(r0 + 128, n);
  float s0 = 0.0f, s1 = 0.0f;
  for (int r = r0 + half; r < rend; r += 2){
    float v = H[(size_t)r * D + c];
    s0 += v; s1 += v * v;
  }
  __shared__ float sm[2][128];
  if (half){ sm[0][c] = s0; sm[1][c] = s1; }
  __syncthreads();
  if (!half){
    s0 += sm[0][c]; s1 += sm[1][c];
    atomicAdd(&bns[c], s0);
    atomicAdd(&bns[D + c], s1);
  }
}

__global__ __launch_bounds__(256) void k_bnnorm(float* __restrict__ H, const float* __restrict__ bns, int n){
  int idx = blockIdx.x * 256 + threadIdx.x;
  if (idx >= n * D) return;
  int c = idx & 127;
  float inv_n = 1.0f / (float)n;
  float mu = bns[c] * inv_n;
  float var = bns[D + c] * inv_n - mu * mu;
  H[idx] = (H[idx] - mu) / sqrtf(var + 1e-5f);
}

// ---------- launch ----------
extern "C" void kernel_launch(void* const* d_in, const int* in_sizes, int n_in,
                              void* d_out, int out_size, void* d_ws, size_t ws_size,
                              hipStream_t stream){
  const float* nf     = (const float*)d_in[0];
  const int*   ei     = (const int*)  d_in[1];
  const float* xprev[2] = { (const float*)d_in[2], (const float*)d_in[3] };
  const float* ts     = (const float*)d_in[4];
  const float* freq   = (const float*)d_in[5];
  const float* phase  = (const float*)d_in[6];
  const float* mergeW = (const float*)d_in[7];
  const float* mergeb = (const float*)d_in[8];
  const float* gatW[2]  = { (const float*)d_in[9],  (const float*)d_in[17] };
  const float* gatAS[2] = { (const float*)d_in[10], (const float*)d_in[18] };
  const float* gatAD[2] = { (const float*)d_in[11], (const float*)d_in[19] };
  const float* gatB[2]  = { (const float*)d_in[12], (const float*)d_in[20] };
  const float* Wih[2]   = { (const float*)d_in[13], (const float*)d_in[21] };
  const float* Whh[2]   = { (const float*)d_in[14], (const float*)d_in[22] };
  const float* bih[2]   = { (const float*)d_in[15], (const float*)d_in[23] };
  const float* bhh[2]   = { (const float*)d_in[16], (const float*)d_in[24] };
  const float* skipW  = (const float*)d_in[25];
  const float* skipb  = (const float*)d_in[26];

  const int n = in_sizes[0] / D;      // 50000
  const int e = in_sizes[1] / 2;      // 640000
  const int etot = e + n;             // 690000
  const size_t nd = (size_t)n * D;

  // workspace carve (4-byte words)
  float* ws   = (float*)d_ws;
  float* asrc = ws;                        // n
  float* adst = asrc + n;                  // n
  float* bns  = adst + n;                  // 2*D
  int*   off  = (int*)(bns + 2 * D);       // n+1
  int*   cnt  = off + n + 1;               // n
  int*   bsum = cnt + n;                   // 256
  int*   csr  = bsum + 256;                // etot
  unsigned short* WTm  = (unsigned short*)(csr + etot);  // 128 x 256
  unsigned short* WTg0 = WTm  + 32768;     // 128 x 128 each
  unsigned short* WTg1 = WTg0 + 16384;
  unsigned short* WTsk = WTg1 + 16384;
  unsigned short* WTih0 = WTsk + 16384;    // 384 x 128 each
  unsigned short* WThh0 = WTih0 + 49152;
  unsigned short* WTih1 = WThh0 + 49152;
  unsigned short* WThh1 = WTih1 + 49152;
  unsigned short* xb   = WThh1 + 49152;    // n*128 bf16
  unsigned short* xpb  = xb  + nd;         // n*128 bf16
  unsigned short* hgb  = xpb + nd;         // n*128 bf16

  float* H1 = (float*)d_out;
  float* H2 = H1 + nd;

  const dim3 b256(256);
  const int nb_nd = (int)((nd + 255) / 256);
  const int nb_e  = (etot + 255) / 256;
  const int nb_n  = (n + 255) / 256;
  const int grows = (n + 63) / 64;         // 782
  const dim3 gm1(1, grows);                // Nc=128 GEMMs
  const int gru_blocks = (n + 63) / 64;    // 782 (512-thread blocks)
  const int nb_wave = (int)(((size_t)n * 64 + 255) / 256);

  // ---- CSR build ----
  k_init0<<<nb_n, b256, 0, stream>>>(cnt, bns, n);
  k_hist<<<nb_e, b256, 0, stream>>>(ei, cnt, e, etot);
  k_scan1<<<nb_n, b256, 0, stream>>>(cnt, off, bsum, n);
  k_scan2<<<1, b256, 0, stream>>>(bsum, nb_n);
  k_scan3<<<nb_n, b256, 0, stream>>>(off, bsum, cnt, n, etot);
  k_scatter<<<nb_e, b256, 0, stream>>>(ei, cnt, csr, e, etot);

  // ---- weight transpose+convert to bf16 ----
  k_wcvt<<<128, b256, 0, stream>>>(mergeW, WTm, 128, 256);
  k_wcvt<<< 64, b256, 0, stream>>>(gatW[0], WTg0, 128, 128);
  k_wcvt<<< 64, b256, 0, stream>>>(gatW[1], WTg1, 128, 128);
  k_wcvt<<< 64, b256, 0, stream>>>(skipW,   WTsk, 128, 128);
  k_wcvt<<<192, b256, 0, stream>>>(Wih[0], WTih0, 384, 128);
  k_wcvt<<<192, b256, 0, stream>>>(Whh[0], WThh0, 384, 128);
  k_wcvt<<<192, b256, 0, stream>>>(Wih[1], WTih1, 384, 128);
  k_wcvt<<<192, b256, 0, stream>>>(Whh[1], WThh1, 384, 128);

  // ---- merge: xb = bf16([nf, cos] @ mergeW + mergeb) ----
  k_merge<<<gm1, b256, 0, stream>>>(nf, ts, freq, phase, WTm, mergeb, xb, n);

  for (int L = 0; L < 2; ++L){
    float* gout = (L == 0) ? H1 : H2;
    const unsigned short* wtg  = (L == 0) ? WTg0 : WTg1;
    const unsigned short* wtih = (L == 0) ? WTih0 : WTih1;
    const unsigned short* wthh = (L == 0) ? WThh0 : WThh1;
    if (L == 0)
      k_mgemm<true , true, false, false><<<gm1, b256, 0, stream>>>(xb, wtg, nullptr, xpb, n, D);
    else
      k_mgemm<false, true, false, false><<<gm1, b256, 0, stream>>>(H1, wtg, nullptr, xpb, n, D);
    k_attn<<<nb_wave, b256, 0, stream>>>(xpb, gatAS[L], gatAD[L], asrc, adst, n);
    k_gatconv<<<nb_wave, b256, 0, stream>>>(off, csr, asrc, adst, xpb, gatB[L], hgb, n);
    if (L == 0)
      k_grugemm<1><<<gru_blocks, dim3(512), 0, stream>>>(hgb, xprev[0], wtih, wthh, bih[0], bhh[0], gout, n);
    else
      k_grugemm<0><<<gru_blocks, dim3(512), 0, stream>>>(hgb, xprev[1], wtih, wthh, bih[1], bhh[1], gout, n);
  }

  // skip: H2 += xb @ skipW + skipb
  k_mgemm<true, false, true, true><<<gm1, b256, 0, stream>>>(xb, WTsk, skipb, H2, n, D);
  // BatchNorm
  k_bnreduce<<<(n + 127) / 128, b256, 0, stream>>>(H2, bns, n);
  k_bnnorm<<<nb_nd, b256, 0, stream>>>(H2, bns, n);
}

// Round 7
// 461.697 us; speedup vs baseline: 3.1847x; 1.0996x over previous
//
#include <hip/hip_runtime.h>
#include <math.h>

#define D 128
#define D3 384

typedef __attribute__((ext_vector_type(8))) short bf16x8;
typedef __attribute__((ext_vector_type(4))) float f32x4;
typedef __attribute__((ext_vector_type(4))) unsigned int u32x4;

// fast transcendentals (native v_exp_f32 / v_rcp_f32 / v_cos_f32)
__device__ __forceinline__ float fsigmoid(float x){
  return __builtin_amdgcn_rcpf(1.0f + __expf(-x));
}
__device__ __forceinline__ float ftanh(float x){
  float e = __expf(2.0f * x);
  return 1.0f - 2.0f * __builtin_amdgcn_rcpf(e + 1.0f);
}

// round-to-nearest-even f32 -> bf16
__device__ __forceinline__ unsigned short f2bf(float f){
  unsigned u = __float_as_uint(f);
  return (unsigned short)((u + 0x7FFFu + ((u >> 16) & 1u)) >> 16);
}

// LDS slot swizzle: lg-disjoint (even/odd) slot sets -> <=2-way at quarter & half wave
__device__ __forceinline__ int slot16(int c, int row){ return (c + 2 * (row & 7)) & 15; }
__device__ __forceinline__ int slot32(int c, int row){ return (c + 2 * (row & 7)) & 31; }

// ---------- zero small scratch ----------
__global__ __launch_bounds__(256) void k_init0(int* __restrict__ cnt, float* __restrict__ bns, int n){
  int idx = blockIdx.x * 256 + threadIdx.x;
  if (idx < n) cnt[idx] = 0;
  if (idx < 2 * D) bns[idx] = 0.0f;
}

// ---------- pack ALL weights into per-wave fragment order (coalesced 1KB loads) ----------
// merge: idx = w*8192 + kk*1024 + nf*512 + lg*128 + l15*8 + j   (w<4, kk<8)
// gat/skip: idx = w*4096 + kk*1024 + nf*512 + lg*128 + l15*8 + j (w<4, kk<4)
// gru: idx = ((w*4+kk)*6 + t)*512 + lg*128 + l15*8 + j (w<8, kk<4, t: 0=ihr,1=hhr,2=ihz,3=hhz,4=ihn,5=hhn)
__global__ __launch_bounds__(256) void k_wpackall(
    const float* __restrict__ mergeW, const float* __restrict__ g0, const float* __restrict__ g1,
    const float* __restrict__ sk, const float* __restrict__ ih0, const float* __restrict__ hh0,
    const float* __restrict__ ih1, const float* __restrict__ hh1,
    unsigned short* __restrict__ Pm, unsigned short* __restrict__ Pg0, unsigned short* __restrict__ Pg1,
    unsigned short* __restrict__ Psk, unsigned short* __restrict__ Pu0, unsigned short* __restrict__ Pu1){
  int idx = blockIdx.x * 256 + threadIdx.x;
  if (idx < 32768){
    int i = idx;
    int j = i & 7, l15 = (i >> 3) & 15, lg = (i >> 7) & 3, nf = (i >> 9) & 1, kk = (i >> 10) & 7, w = (i >> 13) & 3;
    int col = w * 32 + nf * 16 + l15, k = (kk * 4 + lg) * 8 + j;
    Pm[i] = f2bf(mergeW[k * 128 + col]);
  } else if (idx < 81920){
    int seg = (idx - 32768) >> 14;
    int i = (idx - 32768) & 16383;
    const float* W = seg == 0 ? g0 : (seg == 1 ? g1 : sk);
    unsigned short* P = seg == 0 ? Pg0 : (seg == 1 ? Pg1 : Psk);
    int j = i & 7, l15 = (i >> 3) & 15, lg = (i >> 7) & 3, nf = (i >> 9) & 1, kk = (i >> 10) & 3, w = (i >> 12) & 3;
    int col = w * 32 + nf * 16 + l15, k = (kk * 4 + lg) * 8 + j;
    P[i] = f2bf(W[k * 128 + col]);
  } else if (idx < 278528){
    int seg = (idx - 81920) / 98304;
    int i = (idx - 81920) % 98304;
    const float* Wih = seg ? ih1 : ih0;
    const float* Whh = seg ? hh1 : hh0;
    unsigned short* P = seg ? Pu1 : Pu0;
    int j = i & 7, l15 = (i >> 3) & 15, lg = (i >> 7) & 3;
    int r9 = i >> 9; int t = r9 % 6; int r = r9 / 6; int kk = r & 3, w = r >> 2;
    int col = (t >> 1) * 128 + w * 16 + l15, k = (kk * 4 + lg) * 8 + j;
    P[i] = f2bf((t & 1 ? Whh : Wih)[k * 384 + col]);
  }
}

// ---------- merge GEMM: xb = bf16([nf, cos(ts*freq+phase)] @ mergeW + mergeb) ----------
__global__ __launch_bounds__(256) void k_merge(const float* __restrict__ nf, const float* __restrict__ ts,
                                               const float* __restrict__ freq, const float* __restrict__ phase,
                                               const unsigned short* __restrict__ Pm,  // packed
                                               const float* __restrict__ bias,
                                               unsigned short* __restrict__ xb, int M){
  __shared__ __align__(16) unsigned short Alds[64 * 256];   // 32 KB
  const int tid = threadIdx.x;
  const int lane = tid & 63;
  const int w = tid >> 6;
  const int row0 = blockIdx.y * 64;

  #pragma unroll
  for (int r = 0; r < 8; ++r){
    int u = r * 256 + tid;
    int row = u >> 5, c16 = u & 31;
    int gr = row0 + row;
    union { unsigned short s[8]; bf16x8 v; } t;
    if (gr < M){
      if (c16 < 16){
        const float* p = nf + (size_t)gr * 128 + c16 * 8;
        float4 f0 = *(const float4*)p, f1 = *(const float4*)(p + 4);
        t.s[0]=f2bf(f0.x); t.s[1]=f2bf(f0.y); t.s[2]=f2bf(f0.z); t.s[3]=f2bf(f0.w);
        t.s[4]=f2bf(f1.x); t.s[5]=f2bf(f1.y); t.s[6]=f2bf(f1.z); t.s[7]=f2bf(f1.w);
      } else {
        float tv = ts[gr];
        int ch0 = (c16 - 16) * 8;
        float4 fq0 = *(const float4*)&freq[ch0],  fq1 = *(const float4*)&freq[ch0 + 4];
        float4 ph0 = *(const float4*)&phase[ch0], ph1 = *(const float4*)&phase[ch0 + 4];
        t.s[0]=f2bf(__cosf(tv*fq0.x+ph0.x)); t.s[1]=f2bf(__cosf(tv*fq0.y+ph0.y));
        t.s[2]=f2bf(__cosf(tv*fq0.z+ph0.z)); t.s[3]=f2bf(__cosf(tv*fq0.w+ph0.w));
        t.s[4]=f2bf(__cosf(tv*fq1.x+ph1.x)); t.s[5]=f2bf(__cosf(tv*fq1.y+ph1.y));
        t.s[6]=f2bf(__cosf(tv*fq1.z+ph1.z)); t.s[7]=f2bf(__cosf(tv*fq1.w+ph1.w));
      }
    } else {
      #pragma unroll
      for (int q = 0; q < 8; ++q) t.s[q] = 0;
    }
    *(bf16x8*)&Alds[row * 256 + slot32(c16, row) * 8] = t.v;
  }
  __syncthreads();

  f32x4 acc[4][2];
  #pragma unroll
  for (int mf = 0; mf < 4; ++mf)
    #pragma unroll
    for (int nfi = 0; nfi < 2; ++nfi)
      #pragma unroll
      for (int i = 0; i < 4; ++i) acc[mf][nfi][i] = 0.0f;

  const int l15 = lane & 15, lg = lane >> 4;
  #pragma unroll
  for (int kk = 0; kk < 8; ++kk){
    const int c16 = kk * 4 + lg;
    bf16x8 a[4], b[2];
    #pragma unroll
    for (int nfi = 0; nfi < 2; ++nfi)
      b[nfi] = *(const bf16x8*)&Pm[(size_t)((w * 8 + kk) * 2 + nfi) * 512 + lane * 8];
    #pragma unroll
    for (int mf = 0; mf < 4; ++mf){
      int row = mf * 16 + l15;
      a[mf] = *(bf16x8*)&Alds[row * 256 + slot32(c16, row) * 8];
    }
    #pragma unroll
    for (int mf = 0; mf < 4; ++mf)
      #pragma unroll
      for (int nfi = 0; nfi < 2; ++nfi)
        acc[mf][nfi] = __builtin_amdgcn_mfma_f32_16x16x32_bf16(a[mf], b[nfi], acc[mf][nfi], 0, 0, 0);
  }

  #pragma unroll
  for (int nfi = 0; nfi < 2; ++nfi){
    int c = w * 32 + nfi * 16 + l15;
    float bv = bias[c];
    #pragma unroll
    for (int mf = 0; mf < 4; ++mf)
      #pragma unroll
      for (int i = 0; i < 4; ++i){
        int rr = row0 + mf * 16 + lg * 4 + i;
        if (rr < M) xb[(size_t)rr * 128 + c] = f2bf(acc[mf][nfi][i] + bv);
      }
  }
}

// ---------- bf16 MFMA GEMM (Nc=128): C[M,128] (+)= A[M,128] @ W (+ bias) ----------
template<bool ABF16, bool OUTBF, bool ACCUM, bool BIAS>
__global__ __launch_bounds__(256) void k_mgemm(const void* __restrict__ Av,
                                               const unsigned short* __restrict__ Pg,  // packed
                                               const float* __restrict__ bias,
                                               void* __restrict__ Cv, int M){
  __shared__ __align__(16) unsigned short Alds[64 * 128];   // 16 KB
  const int tid = threadIdx.x;
  const int lane = tid & 63;
  const int w = tid >> 6;
  const int row0 = blockIdx.y * 64;

  #pragma unroll
  for (int r = 0; r < 4; ++r){
    int u = r * 256 + tid;
    int row = u >> 4, c16 = u & 15;
    int gr = row0 + row;
    int c16s = slot16(c16, row);
    if (ABF16){
      u32x4 v = {0,0,0,0};
      if (gr < M) v = *(const u32x4*)((const unsigned short*)Av + (size_t)gr * 128 + c16 * 8);
      *(u32x4*)&Alds[row * 128 + c16s * 8] = v;
    } else {
      float4 f0 = make_float4(0.f,0.f,0.f,0.f), f1 = f0;
      if (gr < M){
        const float* p = (const float*)Av + (size_t)gr * 128 + c16 * 8;
        f0 = *(const float4*)p; f1 = *(const float4*)(p + 4);
      }
      union { unsigned short s[8]; bf16x8 v; } t;
      t.s[0]=f2bf(f0.x); t.s[1]=f2bf(f0.y); t.s[2]=f2bf(f0.z); t.s[3]=f2bf(f0.w);
      t.s[4]=f2bf(f1.x); t.s[5]=f2bf(f1.y); t.s[6]=f2bf(f1.z); t.s[7]=f2bf(f1.w);
      *(bf16x8*)&Alds[row * 128 + c16s * 8] = t.v;
    }
  }
  __syncthreads();

  f32x4 acc[4][2];
  #pragma unroll
  for (int mf = 0; mf < 4; ++mf)
    #pragma unroll
    for (int nfi = 0; nfi < 2; ++nfi)
      #pragma unroll
      for (int i = 0; i < 4; ++i) acc[mf][nfi][i] = 0.0f;

  const int l15 = lane & 15, lg = lane >> 4;
  #pragma unroll
  for (int kk = 0; kk < 4; ++kk){
    const int c16 = kk * 4 + lg;
    bf16x8 a[4], b[2];
    #pragma unroll
    for (int nfi = 0; nfi < 2; ++nfi)
      b[nfi] = *(const bf16x8*)&Pg[(size_t)((w * 4 + kk) * 2 + nfi) * 512 + lane * 8];
    #pragma unroll
    for (int mf = 0; mf < 4; ++mf){
      int row = mf * 16 + l15;
      a[mf] = *(bf16x8*)&Alds[row * 128 + slot16(c16, row) * 8];
    }
    #pragma unroll
    for (int mf = 0; mf < 4; ++mf)
      #pragma unroll
      for (int nfi = 0; nfi < 2; ++nfi)
        acc[mf][nfi] = __builtin_amdgcn_mfma_f32_16x16x32_bf16(a[mf], b[nfi], acc[mf][nfi], 0, 0, 0);
  }

  #pragma unroll
  for (int nfi = 0; nfi < 2; ++nfi){
    int c = w * 32 + nfi * 16 + l15;
    float bv = BIAS ? bias[c] : 0.0f;
    #pragma unroll
    for (int mf = 0; mf < 4; ++mf)
      #pragma unroll
      for (int i = 0; i < 4; ++i){
        int rr = row0 + mf * 16 + lg * 4 + i;
        if (rr < M){
          size_t o = (size_t)rr * 128 + c;
          float v = acc[mf][nfi][i] + bv;
          if (OUTBF){
            ((unsigned short*)Cv)[o] = f2bf(v);
          } else {
            float* C = (float*)Cv;
            if (ACCUM) v += C[o];
            C[o] = v;
          }
        }
      }
  }
}

// ---------- attention coefficients from bf16 xpb ----------
__global__ __launch_bounds__(256) void k_attn(const unsigned short* __restrict__ xpb,
                                              const float* __restrict__ a_s, const float* __restrict__ a_d,
                                              float* __restrict__ asrc, float* __restrict__ adst, int n){
  int wave = (blockIdx.x * 256 + threadIdx.x) >> 6;
  int lane = threadIdx.x & 63;
  if (wave >= n) return;
  unsigned u = *(const unsigned*)&xpb[(size_t)wave * D + 2 * lane];
  float lo = __uint_as_float(u << 16);
  float hi = __uint_as_float(u & 0xFFFF0000u);
  float2 as2 = *(const float2*)&a_s[2 * lane];
  float2 ad2 = *(const float2*)&a_d[2 * lane];
  float sa = lo * as2.x + hi * as2.y;
  float sd = lo * ad2.x + hi * ad2.y;
  #pragma unroll
  for (int off = 32; off > 0; off >>= 1){
    sa += __shfl_down(sa, off);
    sd += __shfl_down(sd, off);
  }
  if (lane == 0){ asrc[wave] = sa; adst[wave] = sd; }
}

// ---------- CSR build ----------
__global__ __launch_bounds__(256) void k_hist(const int* __restrict__ ei, int* __restrict__ cnt, int e, int etot){
  int t = blockIdx.x * 256 + threadIdx.x;
  if (t >= etot) return;
  int d_ = (t < e) ? ei[e + t] : (t - e);
  atomicAdd(&cnt[d_], 1);
}

__global__ __launch_bounds__(256) void k_scan1(const int* __restrict__ cnt, int* __restrict__ off,
                                               int* __restrict__ bsum, int n){
  __shared__ int sm[256];
  int i = blockIdx.x * 256 + threadIdx.x;
  int v = (i < n) ? cnt[i] : 0;
  sm[threadIdx.x] = v;
  __syncthreads();
  #pragma unroll
  for (int d = 1; d < 256; d <<= 1){
    int t = (threadIdx.x >= d) ? sm[threadIdx.x - d] : 0;
    __syncthreads();
    sm[threadIdx.x] += t;
    __syncthreads();
  }
  if (i < n) off[i] = sm[threadIdx.x] - v;
  if (threadIdx.x == 255) bsum[blockIdx.x] = sm[255];
}

__global__ __launch_bounds__(256) void k_scan2(int* __restrict__ bsum, int nb){
  __shared__ int sm[256];
  int v = (threadIdx.x < nb) ? bsum[threadIdx.x] : 0;
  sm[threadIdx.x] = v;
  __syncthreads();
  #pragma unroll
  for (int d = 1; d < 256; d <<= 1){
    int t = (threadIdx.x >= d) ? sm[threadIdx.x - d] : 0;
    __syncthreads();
    sm[threadIdx.x] += t;
    __syncthreads();
  }
  if (threadIdx.x < nb) bsum[threadIdx.x] = sm[threadIdx.x] - v;
}

__global__ __launch_bounds__(256) void k_scan3(int* __restrict__ off, const int* __restrict__ bsum,
                                               int* __restrict__ cursor, int n, int etot){
  int i = blockIdx.x * 256 + threadIdx.x;
  if (i < n){
    int o = off[i] + bsum[blockIdx.x];
    off[i] = o;
    cursor[i] = o;
  }
  if (i == 0) off[n] = etot;
}

__global__ __launch_bounds__(256) void k_scatter(const int* __restrict__ ei, int* __restrict__ cursor,
                                                 int* __restrict__ csr, int e, int etot){
  int t = blockIdx.x * 256 + threadIdx.x;
  if (t >= etot) return;
  int s_, d_;
  if (t < e){ s_ = ei[t]; d_ = ei[e + t]; } else { s_ = d_ = t - e; }
  int pos = atomicAdd(&cursor[d_], 1);
  csr[pos] = s_;
}

// ---------- fused GAT edge phase: one wave per dst node, unroll-8 gather MLP ----------
__global__ __launch_bounds__(256) void k_gatconv(const int* __restrict__ off, const int* __restrict__ csr,
                                                 const float* __restrict__ asrc, const float* __restrict__ adst,
                                                 const unsigned short* __restrict__ xpb,
                                                 const float* __restrict__ bias,
                                                 unsigned short* __restrict__ outb, int n){
  int w = (blockIdx.x * 256 + threadIdx.x) >> 6;
  int lane = threadIdx.x & 63;
  if (w >= n) return;
  const int o0 = off[w], o1 = off[w + 1];
  const float ad = adst[w];
  float m = -1e30f;
  for (int j = o0 + lane; j < o1; j += 64){
    float v = asrc[csr[j]] + ad;
    v = (v > 0.0f) ? v : 0.2f * v;
    m = fmaxf(m, v);
  }
  #pragma unroll
  for (int d = 32; d > 0; d >>= 1) m = fmaxf(m, __shfl_xor(m, d));
  float s = 0.0f, acc0 = 0.0f, acc1 = 0.0f;
  for (int base = o0; base < o1; base += 64){
    int j = base + lane;
    float wgt = 0.0f;
    int src = 0;
    if (j < o1){
      src = csr[j];
      float v = asrc[src] + ad;
      v = (v > 0.0f) ? v : 0.2f * v;
      wgt = __expf(v - m);
    }
    s += wgt;
    const int cnt8 = (min(64, o1 - base) + 7) & ~7;
    const int wbits = __float_as_int(wgt);
    for (int t = 0; t < cnt8; t += 8){
      unsigned uu[8]; float wq[8];
      #pragma unroll
      for (int q = 0; q < 8; ++q){
        int sr = __builtin_amdgcn_readlane(src, t + q);
        wq[q] = __int_as_float(__builtin_amdgcn_readlane(wbits, t + q));
        uu[q] = *(const unsigned*)&xpb[(size_t)sr * D + 2 * lane];
      }
      #pragma unroll
      for (int q = 0; q < 8; ++q){
        acc0 = fmaf(wq[q], __uint_as_float(uu[q] << 16), acc0);
        acc1 = fmaf(wq[q], __uint_as_float(uu[q] & 0xFFFF0000u), acc1);
      }
    }
  }
  #pragma unroll
  for (int d = 32; d > 0; d >>= 1) s += __shfl_xor(s, d);
  float inv = 1.0f / (s + 1e-16f);
  float2 bv = *(const float2*)&bias[2 * lane];
  unsigned pack = ((unsigned)f2bf(acc1 * inv + bv.y) << 16) | f2bf(acc0 * inv + bv.x);
  *(unsigned*)&outb[(size_t)w * D + 2 * lane] = pack;
}

// ---------- fused GRU dual-GEMM: BM=64, 8 waves, wave owns 16 H-cols, packed weights ----------
template<int RELU>
__global__ __launch_bounds__(512) void k_grugemm(const unsigned short* __restrict__ hgb,
                                                 const float* __restrict__ xprev,
                                                 const unsigned short* __restrict__ Pu, // packed frag order
                                                 const float* __restrict__ bih,
                                                 const float* __restrict__ bhh,
                                                 float* __restrict__ out, int n){
  __shared__ __align__(16) unsigned short A1lds[64 * 128];  // 16 KB (hg, bf16)
  __shared__ __align__(16) unsigned short A2lds[64 * 128];  // 16 KB (xprev->bf16)
  const int tid = threadIdx.x;
  const int lane = tid & 63;
  const int w = tid >> 6;               // 0..7
  const int row0 = blockIdx.x * 64;

  #pragma unroll
  for (int r = 0; r < 2; ++r){
    int u = r * 512 + tid;
    int row = u >> 4, c16 = u & 15;
    int gr = row0 + row;
    int c16s = slot16(c16, row);
    u32x4 v1 = {0,0,0,0};
    union { unsigned short s[8]; bf16x8 v; } t2;
    #pragma unroll
    for (int q = 0; q < 8; ++q) t2.s[q] = 0;
    if (gr < n){
      v1 = *(const u32x4*)(hgb + (size_t)gr * 128 + c16 * 8);
      const float* p = xprev + (size_t)gr * 128 + c16 * 8;
      float4 f0 = *(const float4*)p, f1 = *(const float4*)(p + 4);
      t2.s[0]=f2bf(f0.x); t2.s[1]=f2bf(f0.y); t2.s[2]=f2bf(f0.z); t2.s[3]=f2bf(f0.w);
      t2.s[4]=f2bf(f1.x); t2.s[5]=f2bf(f1.y); t2.s[6]=f2bf(f1.z); t2.s[7]=f2bf(f1.w);
    }
    *(u32x4*)&A1lds[row * 128 + c16s * 8] = v1;
    *(bf16x8*)&A2lds[row * 128 + c16s * 8] = t2.v;
  }
  __syncthreads();

  f32x4 accR[4], accZ[4], accN[4], accH[4];
  #pragma unroll
  for (int mf = 0; mf < 4; ++mf)
    #pragma unroll
    for (int i = 0; i < 4; ++i){ accR[mf][i]=0.f; accZ[mf][i]=0.f; accN[mf][i]=0.f; accH[mf][i]=0.f; }

  const int l15 = lane & 15, lg = lane >> 4;
  const int cw = w * 16 + l15;          // this lane's output column (0..127)
  #pragma unroll
  for (int kk = 0; kk < 4; ++kk){
    const int c16 = kk * 4 + lg;
    // coalesced packed weight frags: 6 x 1KB contiguous per wave
    const unsigned short* Pb = Pu + (size_t)(w * 4 + kk) * 3072 + lane * 8;
    bf16x8 bir = *(const bf16x8*)&Pb[0];
    bf16x8 bhr = *(const bf16x8*)&Pb[512];
    bf16x8 biz = *(const bf16x8*)&Pb[1024];
    bf16x8 bhz = *(const bf16x8*)&Pb[1536];
    bf16x8 bin = *(const bf16x8*)&Pb[2048];
    bf16x8 bhn = *(const bf16x8*)&Pb[2560];
    bf16x8 a1[4], a2[4];
    #pragma unroll
    for (int mf = 0; mf < 4; ++mf){
      int row = mf * 16 + l15;
      int o = row * 128 + slot16(c16, row) * 8;
      a1[mf] = *(bf16x8*)&A1lds[o];
      a2[mf] = *(bf16x8*)&A2lds[o];
    }
    #pragma unroll
    for (int mf = 0; mf < 4; ++mf){
      accR[mf] = __builtin_amdgcn_mfma_f32_16x16x32_bf16(a1[mf], bir, accR[mf], 0, 0, 0);
      accR[mf] = __builtin_amdgcn_mfma_f32_16x16x32_bf16(a2[mf], bhr, accR[mf], 0, 0, 0);
      accZ[mf] = __builtin_amdgcn_mfma_f32_16x16x32_bf16(a1[mf], biz, accZ[mf], 0, 0, 0);
      accZ[mf] = __builtin_amdgcn_mfma_f32_16x16x32_bf16(a2[mf], bhz, accZ[mf], 0, 0, 0);
      accN[mf] = __builtin_amdgcn_mfma_f32_16x16x32_bf16(a1[mf], bin, accN[mf], 0, 0, 0);
      accH[mf] = __builtin_amdgcn_mfma_f32_16x16x32_bf16(a2[mf], bhn, accH[mf], 0, 0, 0);
    }
  }

  const float sbR = bih[cw] + bhh[cw];
  const float sbZ = bih[cw + 128] + bhh[cw + 128];
  const float biN = bih[cw + 256], bhN = bhh[cw + 256];
  #pragma unroll
  for (int mf = 0; mf < 4; ++mf)
    #pragma unroll
    for (int i = 0; i < 4; ++i){
      int rr = row0 + mf * 16 + lg * 4 + i;
      if (rr < n){
        float r  = fsigmoid(accR[mf][i] + sbR);
        float z  = fsigmoid(accZ[mf][i] + sbZ);
        float nn = ftanh(accN[mf][i] + biN + r * (accH[mf][i] + bhN));
        float hp = xprev[(size_t)rr * 128 + cw];
        float h = (1.0f - z) * nn + z * hp;
        if (RELU) h = fmaxf(h, 0.0f);
        out[(size_t)rr * 128 + cw] = h;
      }
    }
}

// ---------- BatchNorm ----------
__global__ __launch_bounds__(256) void k_bnreduce(const float* __restrict__ H, float* __restrict__ bns, int n){
  int c = threadIdx.x & 127;
  int half = threadIdx.x >> 7;
  int r0 = blockIdx.x * 128;
  int rend = min(r0 + 128, n);
  float s0 = 0.0f, s1 = 0.0f;
  for (int r = r0 + half; r < rend; r += 2){
    float v = H[(size_t)r * D + c];
    s0 += v; s1 += v * v;
  }
  __shared__ float sm[2][128];
  if (half){ sm[0][c] = s0; sm[1][c] = s1; }
  __syncthreads();
  if (!half){
    s0 += sm[0][c]; s1 += sm[1][c];
    atomicAdd(&bns[c], s0);
    atomicAdd(&bns[D + c], s1);
  }
}

__global__ __launch_bounds__(256) void k_bnnorm(float* __restrict__ H, const float* __restrict__ bns, int n){
  int idx = blockIdx.x * 256 + threadIdx.x;
  if (idx >= n * D) return;
  int c = idx & 127;
  float inv_n = 1.0f / (float)n;
  float mu = bns[c] * inv_n;
  float var = bns[D + c] * inv_n - mu * mu;
  H[idx] = (H[idx] - mu) / sqrtf(var + 1e-5f);
}

// ---------- launch ----------
extern "C" void kernel_launch(void* const* d_in, const int* in_sizes, int n_in,
                              void* d_out, int out_size, void* d_ws, size_t ws_size,
                              hipStream_t stream){
  const float* nf     = (const float*)d_in[0];
  const int*   ei     = (const int*)  d_in[1];
  const float* xprev[2] = { (const float*)d_in[2], (const float*)d_in[3] };
  const float* ts     = (const float*)d_in[4];
  const float* freq   = (const float*)d_in[5];
  const float* phase  = (const float*)d_in[6];
  const float* mergeW = (const float*)d_in[7];
  const float* mergeb = (const float*)d_in[8];
  const float* gatW[2]  = { (const float*)d_in[9],  (const float*)d_in[17] };
  const float* gatAS[2] = { (const float*)d_in[10], (const float*)d_in[18] };
  const float* gatAD[2] = { (const float*)d_in[11], (const float*)d_in[19] };
  const float* gatB[2]  = { (const float*)d_in[12], (const float*)d_in[20] };
  const float* Wih[2]   = { (const float*)d_in[13], (const float*)d_in[21] };
  const float* Whh[2]   = { (const float*)d_in[14], (const float*)d_in[22] };
  const float* bih[2]   = { (const float*)d_in[15], (const float*)d_in[23] };
  const float* bhh[2]   = { (const float*)d_in[16], (const float*)d_in[24] };
  const float* skipW  = (const float*)d_in[25];
  const float* skipb  = (const float*)d_in[26];

  const int n = in_sizes[0] / D;      // 50000
  const int e = in_sizes[1] / 2;      // 640000
  const int etot = e + n;             // 690000
  const size_t nd = (size_t)n * D;

  // workspace carve (4-byte words)
  float* ws   = (float*)d_ws;
  float* asrc = ws;                        // n
  float* adst = asrc + n;                  // n
  float* bns  = adst + n;                  // 2*D
  int*   off  = (int*)(bns + 2 * D);       // n+1
  int*   cnt  = off + n + 1;               // n
  int*   bsum = cnt + n;                   // 256
  int*   csr  = bsum + 256;                // etot
  uintptr_t pa = ((uintptr_t)(csr + etot) + 15) & ~(uintptr_t)15;
  unsigned short* Pm  = (unsigned short*)pa;   // 32768 (merge packed)
  unsigned short* Pg0 = Pm  + 32768;           // 16384 each
  unsigned short* Pg1 = Pg0 + 16384;
  unsigned short* Psk = Pg1 + 16384;
  unsigned short* Pu0 = Psk + 16384;           // 98304 each (gru packed)
  unsigned short* Pu1 = Pu0 + 98304;
  unsigned short* xb  = Pu1 + 98304;           // n*128 bf16
  unsigned short* xpb = xb  + nd;              // n*128 bf16
  unsigned short* hgb = xpb + nd;              // n*128 bf16

  float* H1 = (float*)d_out;
  float* H2 = H1 + nd;

  const dim3 b256(256);
  const int nb_nd = (int)((nd + 255) / 256);
  const int nb_e  = (etot + 255) / 256;
  const int nb_n  = (n + 255) / 256;
  const int grows = (n + 63) / 64;         // 782
  const dim3 gm1(1, grows);
  const int gru_blocks = (n + 63) / 64;    // 782 (512-thread blocks)
  const int nb_wave = (int)(((size_t)n * 64 + 255) / 256);

  // ---- CSR build ----
  k_init0<<<nb_n, b256, 0, stream>>>(cnt, bns, n);
  k_hist<<<nb_e, b256, 0, stream>>>(ei, cnt, e, etot);
  k_scan1<<<nb_n, b256, 0, stream>>>(cnt, off, bsum, n);
  k_scan2<<<1, b256, 0, stream>>>(bsum, nb_n);
  k_scan3<<<nb_n, b256, 0, stream>>>(off, bsum, cnt, n, etot);
  k_scatter<<<nb_e, b256, 0, stream>>>(ei, cnt, csr, e, etot);

  // ---- pack all weights (bf16, fragment order) ----
  k_wpackall<<<(278528 + 255) / 256, b256, 0, stream>>>(
      mergeW, gatW[0], gatW[1], skipW, Wih[0], Whh[0], Wih[1], Whh[1],
      Pm, Pg0, Pg1, Psk, Pu0, Pu1);

  // ---- merge: xb = bf16([nf, cos] @ mergeW + mergeb) ----
  k_merge<<<gm1, b256, 0, stream>>>(nf, ts, freq, phase, Pm, mergeb, xb, n);

  for (int L = 0; L < 2; ++L){
    float* gout = (L == 0) ? H1 : H2;
    const unsigned short* wtg = (L == 0) ? Pg0 : Pg1;
    const unsigned short* pu  = (L == 0) ? Pu0 : Pu1;
    if (L == 0)
      k_mgemm<true , true, false, false><<<gm1, b256, 0, stream>>>(xb, wtg, nullptr, xpb, n);
    else
      k_mgemm<false, true, false, false><<<gm1, b256, 0, stream>>>(H1, wtg, nullptr, xpb, n);
    k_attn<<<nb_wave, b256, 0, stream>>>(xpb, gatAS[L], gatAD[L], asrc, adst, n);
    k_gatconv<<<nb_wave, b256, 0, stream>>>(off, csr, asrc, adst, xpb, gatB[L], hgb, n);
    if (L == 0)
      k_grugemm<1><<<gru_blocks, dim3(512), 0, stream>>>(hgb, xprev[0], pu, bih[0], bhh[0], gout, n);
    else
      k_grugemm<0><<<gru_blocks, dim3(512), 0, stream>>>(hgb, xprev[1], pu, bih[1], bhh[1], gout, n);
  }

  // skip: H2 += xb @ skipW + skipb
  k_mgemm<true, false, true, true><<<gm1, b256, 0, stream>>>(xb, Psk, skipb, H2, n);
  // BatchNorm
  k_bnreduce<<<(n + 127) / 128, b256, 0, stream>>>(H2, bns, n);
  k_bnnorm<<<nb_nd, b256, 0, stream>>>(H2, bns, n);
}